// Round 1
// baseline (820.353 us; speedup 1.0000x reference)
//
#include <hip/hip_runtime.h>
#include <hip/hip_bf16.h>

typedef __attribute__((ext_vector_type(8))) short short8;
typedef __attribute__((ext_vector_type(4))) short short4v;
typedef __attribute__((ext_vector_type(4))) float f32x4;

#define MFMA16(a, b, c) __builtin_amdgcn_mfma_f32_16x16x32_bf16(a, b, c, 0, 0, 0)

__device__ __forceinline__ short f2bf(float x) {
  union { float f; unsigned u; } v; v.f = x;
  unsigned u = v.u;
  u += 0x7FFFu + ((u >> 16) & 1u);  // RNE
  return (short)(u >> 16);
}

// ---------------------------------------------------------------------------
// Q projection: (8192x1536) @ (1536x1536), fused RoPE, bf16 out (B,H,S,64)
// ---------------------------------------------------------------------------
__global__ __launch_bounds__(256) void q_proj_kernel(
    const float* __restrict__ hs, const float* __restrict__ wq,
    const float* __restrict__ rc, const float* __restrict__ rsn,
    short* __restrict__ qbuf) {
  const int tid = threadIdx.x;
  const int lane = tid & 63, wid = tid >> 6;
  const int row0 = blockIdx.y * 128, col0 = blockIdx.x * 128;
  const int wr = (wid >> 1) * 64, wc = (wid & 1) * 64;
  const int lr = lane & 15, lk = (lane >> 4) * 8;

  __shared__ short sA[128][40];
  __shared__ short sB[128][40];
  f32x4 acc[4][4] = {};

  for (int kt = 0; kt < 1536; kt += 32) {
#pragma unroll
    for (int p = 0; p < 4; ++p) {
      int idx = (p * 256 + tid) * 4;
      int r = idx >> 5, c = idx & 31;
      const float* src = hs + (size_t)(row0 + r) * 1536 + kt + c;
      f32x4 v = *(const f32x4*)src;
      short4v s4;
      s4[0] = f2bf(v[0]); s4[1] = f2bf(v[1]); s4[2] = f2bf(v[2]); s4[3] = f2bf(v[3]);
      *(short4v*)&sA[r][c] = s4;
    }
#pragma unroll
    for (int p = 0; p < 4; ++p) {
      int idx = (p * 256 + tid) * 4;
      int k = idx >> 7, n = idx & 127;
      const float* src = wq + (size_t)(kt + k) * 1536 + col0 + n;
      f32x4 v = *(const f32x4*)src;
#pragma unroll
      for (int i = 0; i < 4; ++i) sB[n + i][k] = f2bf(v[i]);
    }
    __syncthreads();
    short8 af[4], bf[4];
#pragma unroll
    for (int m = 0; m < 4; ++m) af[m] = *(const short8*)&sA[wr + m * 16 + lr][lk];
#pragma unroll
    for (int n = 0; n < 4; ++n) bf[n] = *(const short8*)&sB[wc + n * 16 + lr][lk];
#pragma unroll
    for (int m = 0; m < 4; ++m)
#pragma unroll
      for (int n = 0; n < 4; ++n) acc[m][n] = MFMA16(af[m], bf[n], acc[m][n]);
    __syncthreads();
  }

  const int h = (col0 + wc) >> 6;
  const int lrow4 = (lane >> 4) * 4;
#pragma unroll
  for (int m = 0; m < 4; ++m) {
#pragma unroll
    for (int r = 0; r < 4; ++r) {
      int grow = row0 + wr + m * 16 + lrow4 + r;
      int b = grow >> 11, t = grow & 2047;
      float v0 = acc[m][0][r], v1 = acc[m][1][r];
      float c0 = rc[t * 32 + lr], s0 = rsn[t * 32 + lr];
      float c1 = rc[t * 32 + 16 + lr], s1 = rsn[t * 32 + 16 + lr];
      float n0 = v0 * c0 - v1 * s0;
      float n1 = v1 * c1 + v0 * s1;
      short* ob = qbuf + ((size_t)(b * 24 + h) * 2048 + t) * 64;
      ob[lr] = f2bf(n0);
      ob[16 + lr] = f2bf(n1);
      ob[32 + lr] = f2bf(acc[m][2][r]);
      ob[48 + lr] = f2bf(acc[m][3][r]);
    }
  }
}

// ---------------------------------------------------------------------------
// K/V projections: (4*rows_pb x 768) @ (768x768).
// transpose==0: out[((b*12+kvh)*rows_pb + key)*64 + d]      (K layout)
// transpose==1: out[((b*12+kvh)*64 + d)*rows_pb + key]      (V^T layout)
// ---------------------------------------------------------------------------
__global__ __launch_bounds__(256) void kv_proj_kernel(
    const float* __restrict__ enc, const float* __restrict__ W,
    short* __restrict__ out, int rlog2, int text_off, int transpose) {
  const int tid = threadIdx.x;
  const int lane = tid & 63, wid = tid >> 6;
  const int row0 = blockIdx.y * 128, col0 = blockIdx.x * 128;
  const int wr = (wid >> 1) * 64, wc = (wid & 1) * 64;
  const int lr = lane & 15, lk = (lane >> 4) * 8;
  const int rmask = (1 << rlog2) - 1;

  __shared__ short sA[128][40];
  __shared__ short sB[128][40];
  f32x4 acc[4][4] = {};

  for (int kt = 0; kt < 768; kt += 32) {
#pragma unroll
    for (int p = 0; p < 4; ++p) {
      int idx = (p * 256 + tid) * 4;
      int r = idx >> 5, c = idx & 31;
      int m = row0 + r;
      int b = m >> rlog2, key = m & rmask;
      const float* src = enc + (size_t)(b * 576 + text_off + key) * 768 + kt + c;
      f32x4 v = *(const f32x4*)src;
      short4v s4;
      s4[0] = f2bf(v[0]); s4[1] = f2bf(v[1]); s4[2] = f2bf(v[2]); s4[3] = f2bf(v[3]);
      *(short4v*)&sA[r][c] = s4;
    }
#pragma unroll
    for (int p = 0; p < 4; ++p) {
      int idx = (p * 256 + tid) * 4;
      int k = idx >> 7, n = idx & 127;
      const float* src = W + (size_t)(kt + k) * 768 + col0 + n;
      f32x4 v = *(const f32x4*)src;
#pragma unroll
      for (int i = 0; i < 4; ++i) sB[n + i][k] = f2bf(v[i]);
    }
    __syncthreads();
    short8 af[4], bf[4];
#pragma unroll
    for (int m = 0; m < 4; ++m) af[m] = *(const short8*)&sA[wr + m * 16 + lr][lk];
#pragma unroll
    for (int n = 0; n < 4; ++n) bf[n] = *(const short8*)&sB[wc + n * 16 + lr][lk];
#pragma unroll
    for (int m = 0; m < 4; ++m)
#pragma unroll
      for (int n = 0; n < 4; ++n) acc[m][n] = MFMA16(af[m], bf[n], acc[m][n]);
    __syncthreads();
  }

  const int lrow4 = (lane >> 4) * 4;
#pragma unroll
  for (int m = 0; m < 4; ++m) {
#pragma unroll
    for (int n = 0; n < 4; ++n) {
#pragma unroll
      for (int r = 0; r < 4; ++r) {
        int grow = row0 + wr + m * 16 + lrow4 + r;
        int gcol = col0 + wc + n * 16 + lr;
        int b = grow >> rlog2, key = grow & rmask;
        int kvh = gcol >> 6, d = gcol & 63;
        size_t o;
        if (transpose)
          o = ((size_t)((b * 12 + kvh) * 64 + d) << rlog2) + key;
        else
          o = (((size_t)(b * 12 + kvh) << rlog2) + key) * 64 + d;
        out[o] = f2bf(acc[m][n][r]);
      }
    }
  }
}

// ---------------------------------------------------------------------------
// Attention: block = (b, h, 64 q rows), 4 waves x 16 rows.
// Two independent online-softmax passes (text 512 keys, ip 64 keys), summed.
// ---------------------------------------------------------------------------
template <int NKF, int KSPV>
__device__ __forceinline__ void attn_pass(
    const short* __restrict__ kp, const short* __restrict__ vp, int vstride,
    int ntiles, const short8 qf[2], short (*sP)[136],
    float m_run[4], float l_run[4], f32x4 o_acc[4], int lane) {
  const int lr = lane & 15, lk = (lane >> 4) * 8, lrow4 = (lane >> 4) * 4;
  for (int kt = 0; kt < ntiles; ++kt) {
    f32x4 s[NKF];
#pragma unroll
    for (int nf = 0; nf < NKF; ++nf) {
      const short* kb = kp + (size_t)(kt * (NKF * 16) + nf * 16 + lr) * 64 + lk;
      short8 k0 = *(const short8*)kb;
      short8 k1 = *(const short8*)(kb + 32);
      f32x4 a = {0.f, 0.f, 0.f, 0.f};
      a = MFMA16(qf[0], k0, a);
      a = MFMA16(qf[1], k1, a);
      s[nf] = a;
    }
#pragma unroll
    for (int r = 0; r < 4; ++r) {
#pragma unroll
      for (int nf = 0; nf < NKF; ++nf) s[nf][r] *= 0.125f;  // 1/sqrt(64)
      float mx = s[0][r];
#pragma unroll
      for (int nf = 1; nf < NKF; ++nf) mx = fmaxf(mx, s[nf][r]);
      mx = fmaxf(mx, __shfl_xor(mx, 1));
      mx = fmaxf(mx, __shfl_xor(mx, 2));
      mx = fmaxf(mx, __shfl_xor(mx, 4));
      mx = fmaxf(mx, __shfl_xor(mx, 8));
      float mn = fmaxf(m_run[r], mx);
      float corr = __expf(m_run[r] - mn);
      m_run[r] = mn;
      float rs = 0.f;
#pragma unroll
      for (int nf = 0; nf < NKF; ++nf) {
        float p = __expf(s[nf][r] - mn);
        s[nf][r] = p;
        rs += p;
      }
      rs += __shfl_xor(rs, 1);
      rs += __shfl_xor(rs, 2);
      rs += __shfl_xor(rs, 4);
      rs += __shfl_xor(rs, 8);
      l_run[r] = l_run[r] * corr + rs;
#pragma unroll
      for (int no = 0; no < 4; ++no) o_acc[no][r] *= corr;
    }
#pragma unroll
    for (int nf = 0; nf < NKF; ++nf)
#pragma unroll
      for (int r = 0; r < 4; ++r) sP[lrow4 + r][nf * 16 + lr] = f2bf(s[nf][r]);
    __syncthreads();
#pragma unroll
    for (int ks = 0; ks < KSPV; ++ks) {
      short8 pa = *(const short8*)&sP[lr][ks * 32 + lk];
#pragma unroll
      for (int no = 0; no < 4; ++no) {
        const short* vb =
            vp + (size_t)(no * 16 + lr) * vstride + kt * (NKF * 16) + ks * 32 + lk;
        short8 vf = *(const short8*)vb;
        o_acc[no] = MFMA16(pa, vf, o_acc[no]);
      }
    }
    __syncthreads();
  }
}

__global__ __launch_bounds__(256) void attn_kernel(
    const short* __restrict__ qbuf, const short* __restrict__ kbuf,
    const short* __restrict__ vtbuf, const short* __restrict__ kipbuf,
    const short* __restrict__ vtipbuf, short* __restrict__ attn_out) {
  const int tid = threadIdx.x;
  const int lane = tid & 63, wid = tid >> 6;
  const int qt = blockIdx.x;   // 0..31
  const int h = blockIdx.y;    // 0..23
  const int b = blockIdx.z;    // 0..3
  const int kvh = h >> 1;
  const int lr = lane & 15, lk = (lane >> 4) * 8, lrow4 = (lane >> 4) * 4;

  __shared__ short sPall[4][16][136];
  short(*sP)[136] = sPall[wid];

  const short* qp = qbuf + (size_t)(b * 24 + h) * 2048 * 64;
  const short* kp = kbuf + (size_t)(b * 12 + kvh) * 512 * 64;
  const short* vp = vtbuf + (size_t)(b * 12 + kvh) * 64 * 512;
  const short* kip = kipbuf + (size_t)(b * 12 + kvh) * 64 * 64;
  const short* vip = vtipbuf + (size_t)(b * 12 + kvh) * 64 * 64;

  const int q0 = qt * 64 + wid * 16;
  short8 qf[2];
  qf[0] = *(const short8*)(qp + (size_t)(q0 + lr) * 64 + lk);
  qf[1] = *(const short8*)(qp + (size_t)(q0 + lr) * 64 + 32 + lk);

  float m_run[4] = {-3.0e38f, -3.0e38f, -3.0e38f, -3.0e38f};
  float l_run[4] = {0.f, 0.f, 0.f, 0.f};
  f32x4 o_acc[4] = {};

  attn_pass<8, 4>(kp, vp, 512, 4, qf, sP, m_run, l_run, o_acc, lane);

  float o_fin[4][4];
#pragma unroll
  for (int r = 0; r < 4; ++r) {
    float inv = 1.0f / l_run[r];
#pragma unroll
    for (int no = 0; no < 4; ++no) o_fin[no][r] = o_acc[no][r] * inv;
    m_run[r] = -3.0e38f;
    l_run[r] = 0.f;
  }
#pragma unroll
  for (int no = 0; no < 4; ++no) o_acc[no] = f32x4{0.f, 0.f, 0.f, 0.f};

  attn_pass<4, 2>(kip, vip, 64, 1, qf, sP, m_run, l_run, o_acc, lane);

#pragma unroll
  for (int r = 0; r < 4; ++r) {
    float inv = 1.0f / l_run[r];
    int grow = b * 2048 + q0 + lrow4 + r;
#pragma unroll
    for (int no = 0; no < 4; ++no) {
      float val = o_fin[no][r] + o_acc[no][r] * inv;  // IP_SCALE = 1
      attn_out[(size_t)grow * 1536 + h * 64 + no * 16 + lr] = f2bf(val);
    }
  }
}

// ---------------------------------------------------------------------------
// Output projection: (8192x1536 bf16) @ (1536x1536 f32) + bo + residual -> f32
// ---------------------------------------------------------------------------
__global__ __launch_bounds__(256) void o_proj_kernel(
    const short* __restrict__ attn, const float* __restrict__ wo,
    const float* __restrict__ bo, const float* __restrict__ resid,
    float* __restrict__ out) {
  const int tid = threadIdx.x;
  const int lane = tid & 63, wid = tid >> 6;
  const int row0 = blockIdx.y * 128, col0 = blockIdx.x * 128;
  const int wr = (wid >> 1) * 64, wc = (wid & 1) * 64;
  const int lr = lane & 15, lk = (lane >> 4) * 8;

  __shared__ short sA[128][40];
  __shared__ short sB[128][40];
  f32x4 acc[4][4] = {};

  for (int kt = 0; kt < 1536; kt += 32) {
#pragma unroll
    for (int p = 0; p < 2; ++p) {
      int idx = (p * 256 + tid) * 8;
      int r = idx >> 5, c = idx & 31;
      *(short8*)&sA[r][c] = *(const short8*)(attn + (size_t)(row0 + r) * 1536 + kt + c);
    }
#pragma unroll
    for (int p = 0; p < 4; ++p) {
      int idx = (p * 256 + tid) * 4;
      int k = idx >> 7, n = idx & 127;
      const float* src = wo + (size_t)(kt + k) * 1536 + col0 + n;
      f32x4 v = *(const f32x4*)src;
#pragma unroll
      for (int i = 0; i < 4; ++i) sB[n + i][k] = f2bf(v[i]);
    }
    __syncthreads();
    short8 af[4], bf[4];
#pragma unroll
    for (int m = 0; m < 4; ++m) af[m] = *(const short8*)&sA[wr + m * 16 + lr][lk];
#pragma unroll
    for (int n = 0; n < 4; ++n) bf[n] = *(const short8*)&sB[wc + n * 16 + lr][lk];
#pragma unroll
    for (int m = 0; m < 4; ++m)
#pragma unroll
      for (int n = 0; n < 4; ++n) acc[m][n] = MFMA16(af[m], bf[n], acc[m][n]);
    __syncthreads();
  }

  const int lrow4 = (lane >> 4) * 4;
#pragma unroll
  for (int m = 0; m < 4; ++m) {
#pragma unroll
    for (int n = 0; n < 4; ++n) {
#pragma unroll
      for (int r = 0; r < 4; ++r) {
        int grow = row0 + wr + m * 16 + lrow4 + r;
        int gcol = col0 + wc + n * 16 + lr;
        size_t off = (size_t)grow * 1536 + gcol;
        out[off] = acc[m][n][r] + bo[gcol] + resid[off];
      }
    }
  }
}

// ---------------------------------------------------------------------------
extern "C" void kernel_launch(void* const* d_in, const int* in_sizes, int n_in,
                              void* d_out, int out_size, void* d_ws, size_t ws_size,
                              hipStream_t stream) {
  const float* hs = (const float*)d_in[0];
  const float* enc = (const float*)d_in[1];
  const float* rc = (const float*)d_in[2];
  const float* rsn = (const float*)d_in[3];
  const float* wq = (const float*)d_in[4];
  const float* wk = (const float*)d_in[5];
  const float* wv = (const float*)d_in[6];
  const float* wkip = (const float*)d_in[7];
  const float* wvip = (const float*)d_in[8];
  const float* wo = (const float*)d_in[9];
  const float* bo = (const float*)d_in[10];
  float* out = (float*)d_out;

  char* ws = (char*)d_ws;
  short* qbuf = (short*)ws;                         // 4*24*2048*64*2 = 25165824
  short* kbuf = (short*)(ws + 25165824);            // 4*12*512*64*2  =  3145728
  short* vtbuf = (short*)(ws + 28311552);           //                   3145728
  short* kipbuf = (short*)(ws + 31457280);          // 4*12*64*64*2   =   393216
  short* vtipbuf = (short*)(ws + 31850496);         //                    393216
  short* attnbuf = (short*)(ws + 32243712);         // 8192*1536*2    = 25165824
  // total 57409536 bytes

  q_proj_kernel<<<dim3(12, 64), 256, 0, stream>>>(hs, wq, rc, rsn, qbuf);
  kv_proj_kernel<<<dim3(6, 16), 256, 0, stream>>>(enc, wk, kbuf, 9, 0, 0);
  kv_proj_kernel<<<dim3(6, 16), 256, 0, stream>>>(enc, wv, vtbuf, 9, 0, 1);
  kv_proj_kernel<<<dim3(6, 2), 256, 0, stream>>>(enc, wkip, kipbuf, 6, 512, 0);
  kv_proj_kernel<<<dim3(6, 2), 256, 0, stream>>>(enc, wvip, vtipbuf, 6, 512, 1);
  attn_kernel<<<dim3(32, 24, 4), 256, 0, stream>>>(qbuf, kbuf, vtbuf, kipbuf,
                                                   vtipbuf, attnbuf);
  o_proj_kernel<<<dim3(12, 64), 256, 0, stream>>>(attnbuf, wo, bo, hs, out);
}

// Round 2
// 416.181 us; speedup vs baseline: 1.9711x; 1.9711x over previous
//
#include <hip/hip_runtime.h>
#include <hip/hip_bf16.h>

typedef __attribute__((ext_vector_type(8))) short short8;
typedef __attribute__((ext_vector_type(4))) short short4v;
typedef __attribute__((ext_vector_type(4))) float f32x4;

#define MFMA16(a, b, c) __builtin_amdgcn_mfma_f32_16x16x32_bf16(a, b, c, 0, 0, 0)

__device__ __forceinline__ short f2bf(float x) {
  union { float f; unsigned u; } v; v.f = x;
  unsigned u = v.u;
  u += 0x7FFFu + ((u >> 16) & 1u);  // RNE
  return (short)(u >> 16);
}

__device__ __forceinline__ void gload16(const void* g, void* l) {
  __builtin_amdgcn_global_load_lds(
      (const __attribute__((address_space(1))) unsigned int*)g,
      (__attribute__((address_space(3))) unsigned int*)l, 16, 0, 0);
}

// ---------------------------------------------------------------------------
// Pre-pass kernels: f32 -> bf16 convert / pack / transpose
// ---------------------------------------------------------------------------
__global__ __launch_bounds__(256) void conv_bf16_kernel(
    const float* __restrict__ in, short* __restrict__ out, int n4) {
  int i = blockIdx.x * 256 + threadIdx.x;
  if (i >= n4) return;
  f32x4 v = *(const f32x4*)(in + (size_t)i * 4);
  short4v s;
  s[0] = f2bf(v[0]); s[1] = f2bf(v[1]); s[2] = f2bf(v[2]); s[3] = f2bf(v[3]);
  *(short4v*)(out + (size_t)i * 4) = s;
}

// enc (4 x 576 x 768 f32) -> text_bf (4*512 x 768) + ip_bf (4*64 x 768)
__global__ __launch_bounds__(256) void enc_pack_kernel(
    const float* __restrict__ enc, short* __restrict__ text,
    short* __restrict__ ip) {
  int i4 = blockIdx.x * 256 + threadIdx.x;
  int i = i4 * 4;
  if (i >= 4 * 576 * 768) return;
  int c = i % 768;
  int rs = i / 768;
  int b = rs / 576, s = rs % 576;
  f32x4 v = *(const f32x4*)(enc + i);
  short4v o;
  o[0] = f2bf(v[0]); o[1] = f2bf(v[1]); o[2] = f2bf(v[2]); o[3] = f2bf(v[3]);
  if (s < 512)
    *(short4v*)(text + (size_t)(b * 512 + s) * 768 + c) = o;
  else
    *(short4v*)(ip + (size_t)(b * 64 + (s - 512)) * 768 + c) = o;
}

// in: K x N f32 row-major -> out: (N x K) bf16 row-major at row offset
__global__ __launch_bounds__(256) void transpose_conv_kernel(
    const float* __restrict__ in, short* __restrict__ out, int K, int N,
    int row_off, int out_ld) {
  __shared__ float tile[32][33];
  int c0 = blockIdx.x * 32, r0 = blockIdx.y * 32;
  int tx = threadIdx.x & 31, ty = threadIdx.x >> 5;  // ty 0..7
#pragma unroll
  for (int j = 0; j < 4; ++j)
    tile[ty + j * 8][tx] = in[(size_t)(r0 + ty + j * 8) * N + c0 + tx];
  __syncthreads();
#pragma unroll
  for (int j = 0; j < 4; ++j)
    out[(size_t)(row_off + c0 + ty + j * 8) * out_ld + r0 + tx] =
        f2bf(tile[tx][ty + j * 8]);
}

// ---------------------------------------------------------------------------
// Shared GEMM core: 128x128 tile, BK=64, global_load_lds + XOR swizzle (T2,
// both-sides per rule #21), 4 waves (2x2), 16x16x32 bf16 MFMA.
// A: M x K bf16 row-major (lda), Bt: N x K bf16 row-major (ldb).
// ---------------------------------------------------------------------------
__device__ __forceinline__ void gemm_core(
    const short* __restrict__ A, const short* __restrict__ Bt, int K, int lda,
    int ldb, int row0, int col0, short* sA, short* sB, f32x4 acc[4][4]) {
  const int tid = threadIdx.x;
  const int lane = tid & 63;
  const int wid = tid >> 6;
  const int wr = (wid >> 1) * 64, wc = (wid & 1) * 64;
  const int lr = lane & 15;
  const int hk = (lane >> 4) * 16;   // byte offset of this lane's 8-elem group
  const int xr = (lr & 7) << 4;      // read-side XOR swizzle

  for (int kt = 0; kt < K; kt += 64) {
#pragma unroll
    for (int q = 0; q < 4; ++q) {
      int L = q * 4096 + tid * 16;           // linear LDS byte
      int r = L >> 7;                        // tile row (128B rows)
      int sb = (L & 127) ^ ((r & 7) << 4);   // inverse-swizzled source col byte
      int srcoff = kt + (sb >> 1);
      gload16(A + (size_t)(row0 + r) * lda + srcoff, (char*)sA + L);
      gload16(Bt + (size_t)(col0 + r) * ldb + srcoff, (char*)sB + L);
    }
    __syncthreads();
#pragma unroll
    for (int kk = 0; kk < 2; ++kk) {
      short8 af[4], bf[4];
#pragma unroll
      for (int m = 0; m < 4; ++m) {
        int row = wr + m * 16 + lr;
        af[m] = *(const short8*)((const char*)sA + row * 128 +
                                 ((kk * 64 + hk) ^ xr));
      }
#pragma unroll
      for (int n = 0; n < 4; ++n) {
        int row = wc + n * 16 + lr;
        bf[n] = *(const short8*)((const char*)sB + row * 128 +
                                 ((kk * 64 + hk) ^ xr));
      }
#pragma unroll
      for (int m = 0; m < 4; ++m)
#pragma unroll
        for (int n = 0; n < 4; ++n) acc[m][n] = MFMA16(af[m], bf[n], acc[m][n]);
    }
    __syncthreads();
  }
}

// ---------------------------------------------------------------------------
// Q projection GEMM + RoPE epilogue -> qbuf bf16 (B,H,S,64)
// ---------------------------------------------------------------------------
__global__ __launch_bounds__(256) void q_proj_gemm(
    const short* __restrict__ hsbf, const short* __restrict__ wqT,
    const float* __restrict__ rc, const float* __restrict__ rsn,
    short* __restrict__ qbuf) {
  __shared__ short sA[128 * 64];
  __shared__ short sB[128 * 64];
  f32x4 acc[4][4] = {};
  const int row0 = blockIdx.y * 128, col0 = blockIdx.x * 128;
  gemm_core(hsbf, wqT, 1536, 1536, 1536, row0, col0, sA, sB, acc);

  const int tid = threadIdx.x;
  const int lane = tid & 63, wid = tid >> 6;
  const int wr = (wid >> 1) * 64, wc = (wid & 1) * 64;
  const int lr = lane & 15, lrow4 = (lane >> 4) * 4;
  const int h = (col0 + wc) >> 6;
#pragma unroll
  for (int m = 0; m < 4; ++m) {
#pragma unroll
    for (int r = 0; r < 4; ++r) {
      int grow = row0 + wr + m * 16 + lrow4 + r;
      int b = grow >> 11, t = grow & 2047;
      float v0 = acc[m][0][r], v1 = acc[m][1][r];
      float c0 = rc[t * 32 + lr], s0 = rsn[t * 32 + lr];
      float c1 = rc[t * 32 + 16 + lr], s1 = rsn[t * 32 + 16 + lr];
      float n0 = v0 * c0 - v1 * s0;
      float n1 = v1 * c1 + v0 * s1;
      short* ob = qbuf + ((size_t)(b * 24 + h) * 2048 + t) * 64;
      ob[lr] = f2bf(n0);
      ob[16 + lr] = f2bf(n1);
      ob[32 + lr] = f2bf(acc[m][2][r]);
      ob[48 + lr] = f2bf(acc[m][3][r]);
    }
  }
}

// ---------------------------------------------------------------------------
// Fused K|V projection GEMM (B^T = [wkT ; wvT], N=1536).
// cols 0..767 -> K layout  out[((b*12+kvh)<<rlog2)+key]*64 + d
// cols 768..  -> V^T layout out[((b*12+kvh)*64+d)<<rlog2] + key
// ---------------------------------------------------------------------------
__global__ __launch_bounds__(256) void kv_gemm(
    const short* __restrict__ Abf, const short* __restrict__ wkvT,
    short* __restrict__ kout, short* __restrict__ vtout, int rlog2) {
  __shared__ short sA[128 * 64];
  __shared__ short sB[128 * 64];
  f32x4 acc[4][4] = {};
  const int row0 = blockIdx.y * 128, col0 = blockIdx.x * 128;
  gemm_core(Abf, wkvT, 768, 768, 768, row0, col0, sA, sB, acc);

  const int tid = threadIdx.x;
  const int lane = tid & 63, wid = tid >> 6;
  const int wr = (wid >> 1) * 64, wc = (wid & 1) * 64;
  const int lr = lane & 15, lrow4 = (lane >> 4) * 4;
  const int rmask = (1 << rlog2) - 1;
#pragma unroll
  for (int m = 0; m < 4; ++m) {
#pragma unroll
    for (int n = 0; n < 4; ++n) {
#pragma unroll
      for (int r = 0; r < 4; ++r) {
        int grow = row0 + wr + m * 16 + lrow4 + r;
        int gcol = col0 + wc + n * 16 + lr;
        int b = grow >> rlog2, key = grow & rmask;
        short val = f2bf(acc[m][n][r]);
        if (gcol < 768) {
          int kvh = gcol >> 6, d = gcol & 63;
          kout[((((size_t)(b * 12 + kvh)) << rlog2) + key) * 64 + d] = val;
        } else {
          int c2 = gcol - 768;
          int kvh = c2 >> 6, d = c2 & 63;
          vtout[(((size_t)((b * 12 + kvh) * 64 + d)) << rlog2) + key] = val;
        }
      }
    }
  }
}

// ---------------------------------------------------------------------------
// Output projection GEMM + bias + residual -> f32
// ---------------------------------------------------------------------------
__global__ __launch_bounds__(256) void o_proj_gemm(
    const short* __restrict__ attnbf, const short* __restrict__ woT,
    const float* __restrict__ bo, const float* __restrict__ resid,
    float* __restrict__ out) {
  __shared__ short sA[128 * 64];
  __shared__ short sB[128 * 64];
  f32x4 acc[4][4] = {};
  const int row0 = blockIdx.y * 128, col0 = blockIdx.x * 128;
  gemm_core(attnbf, woT, 1536, 1536, 1536, row0, col0, sA, sB, acc);

  const int tid = threadIdx.x;
  const int lane = tid & 63, wid = tid >> 6;
  const int wr = (wid >> 1) * 64, wc = (wid & 1) * 64;
  const int lr = lane & 15, lrow4 = (lane >> 4) * 4;
#pragma unroll
  for (int m = 0; m < 4; ++m) {
#pragma unroll
    for (int n = 0; n < 4; ++n) {
#pragma unroll
      for (int r = 0; r < 4; ++r) {
        int grow = row0 + wr + m * 16 + lrow4 + r;
        int gcol = col0 + wc + n * 16 + lr;
        size_t off = (size_t)grow * 1536 + gcol;
        out[off] = acc[m][n][r] + bo[gcol] + resid[off];
      }
    }
  }
}

// ---------------------------------------------------------------------------
// Attention (unchanged from round 1): block = (b, h, 64 q rows), 4 waves.
// ---------------------------------------------------------------------------
template <int NKF, int KSPV>
__device__ __forceinline__ void attn_pass(
    const short* __restrict__ kp, const short* __restrict__ vp, int vstride,
    int ntiles, const short8 qf[2], short (*sP)[136],
    float m_run[4], float l_run[4], f32x4 o_acc[4], int lane) {
  const int lr = lane & 15, lk = (lane >> 4) * 8, lrow4 = (lane >> 4) * 4;
  for (int kt = 0; kt < ntiles; ++kt) {
    f32x4 s[NKF];
#pragma unroll
    for (int nf = 0; nf < NKF; ++nf) {
      const short* kb = kp + (size_t)(kt * (NKF * 16) + nf * 16 + lr) * 64 + lk;
      short8 k0 = *(const short8*)kb;
      short8 k1 = *(const short8*)(kb + 32);
      f32x4 a = {0.f, 0.f, 0.f, 0.f};
      a = MFMA16(qf[0], k0, a);
      a = MFMA16(qf[1], k1, a);
      s[nf] = a;
    }
#pragma unroll
    for (int r = 0; r < 4; ++r) {
#pragma unroll
      for (int nf = 0; nf < NKF; ++nf) s[nf][r] *= 0.125f;  // 1/sqrt(64)
      float mx = s[0][r];
#pragma unroll
      for (int nf = 1; nf < NKF; ++nf) mx = fmaxf(mx, s[nf][r]);
      mx = fmaxf(mx, __shfl_xor(mx, 1));
      mx = fmaxf(mx, __shfl_xor(mx, 2));
      mx = fmaxf(mx, __shfl_xor(mx, 4));
      mx = fmaxf(mx, __shfl_xor(mx, 8));
      float mn = fmaxf(m_run[r], mx);
      float corr = __expf(m_run[r] - mn);
      m_run[r] = mn;
      float rs = 0.f;
#pragma unroll
      for (int nf = 0; nf < NKF; ++nf) {
        float p = __expf(s[nf][r] - mn);
        s[nf][r] = p;
        rs += p;
      }
      rs += __shfl_xor(rs, 1);
      rs += __shfl_xor(rs, 2);
      rs += __shfl_xor(rs, 4);
      rs += __shfl_xor(rs, 8);
      l_run[r] = l_run[r] * corr + rs;
#pragma unroll
      for (int no = 0; no < 4; ++no) o_acc[no][r] *= corr;
    }
#pragma unroll
    for (int nf = 0; nf < NKF; ++nf)
#pragma unroll
      for (int r = 0; r < 4; ++r) sP[lrow4 + r][nf * 16 + lr] = f2bf(s[nf][r]);
    __syncthreads();
#pragma unroll
    for (int ks = 0; ks < KSPV; ++ks) {
      short8 pa = *(const short8*)&sP[lr][ks * 32 + lk];
#pragma unroll
      for (int no = 0; no < 4; ++no) {
        const short* vb =
            vp + (size_t)(no * 16 + lr) * vstride + kt * (NKF * 16) + ks * 32 + lk;
        short8 vf = *(const short8*)vb;
        o_acc[no] = MFMA16(pa, vf, o_acc[no]);
      }
    }
    __syncthreads();
  }
}

__global__ __launch_bounds__(256) void attn_kernel(
    const short* __restrict__ qbuf, const short* __restrict__ kbuf,
    const short* __restrict__ vtbuf, const short* __restrict__ kipbuf,
    const short* __restrict__ vtipbuf, short* __restrict__ attn_out) {
  const int tid = threadIdx.x;
  const int lane = tid & 63, wid = tid >> 6;
  const int qt = blockIdx.x;   // 0..31
  const int h = blockIdx.y;    // 0..23
  const int b = blockIdx.z;    // 0..3
  const int kvh = h >> 1;
  const int lr = lane & 15, lk = (lane >> 4) * 8, lrow4 = (lane >> 4) * 4;

  __shared__ short sPall[4][16][136];
  short(*sP)[136] = sPall[wid];

  const short* qp = qbuf + (size_t)(b * 24 + h) * 2048 * 64;
  const short* kp = kbuf + (size_t)(b * 12 + kvh) * 512 * 64;
  const short* vp = vtbuf + (size_t)(b * 12 + kvh) * 64 * 512;
  const short* kip = kipbuf + (size_t)(b * 12 + kvh) * 64 * 64;
  const short* vip = vtipbuf + (size_t)(b * 12 + kvh) * 64 * 64;

  const int q0 = qt * 64 + wid * 16;
  short8 qf[2];
  qf[0] = *(const short8*)(qp + (size_t)(q0 + lr) * 64 + lk);
  qf[1] = *(const short8*)(qp + (size_t)(q0 + lr) * 64 + 32 + lk);

  float m_run[4] = {-3.0e38f, -3.0e38f, -3.0e38f, -3.0e38f};
  float l_run[4] = {0.f, 0.f, 0.f, 0.f};
  f32x4 o_acc[4] = {};

  attn_pass<8, 4>(kp, vp, 512, 4, qf, sP, m_run, l_run, o_acc, lane);

  float o_fin[4][4];
#pragma unroll
  for (int r = 0; r < 4; ++r) {
    float inv = 1.0f / l_run[r];
#pragma unroll
    for (int no = 0; no < 4; ++no) o_fin[no][r] = o_acc[no][r] * inv;
    m_run[r] = -3.0e38f;
    l_run[r] = 0.f;
  }
#pragma unroll
  for (int no = 0; no < 4; ++no) o_acc[no] = f32x4{0.f, 0.f, 0.f, 0.f};

  attn_pass<4, 2>(kip, vip, 64, 1, qf, sP, m_run, l_run, o_acc, lane);

#pragma unroll
  for (int r = 0; r < 4; ++r) {
    float inv = 1.0f / l_run[r];
    int grow = b * 2048 + q0 + lrow4 + r;
#pragma unroll
    for (int no = 0; no < 4; ++no) {
      float val = o_fin[no][r] + o_acc[no][r] * inv;  // IP_SCALE = 1
      attn_out[(size_t)grow * 1536 + h * 64 + no * 16 + lr] = f2bf(val);
    }
  }
}

// ---------------------------------------------------------------------------
extern "C" void kernel_launch(void* const* d_in, const int* in_sizes, int n_in,
                              void* d_out, int out_size, void* d_ws, size_t ws_size,
                              hipStream_t stream) {
  const float* hs = (const float*)d_in[0];
  const float* enc = (const float*)d_in[1];
  const float* rc = (const float*)d_in[2];
  const float* rsn = (const float*)d_in[3];
  const float* wq = (const float*)d_in[4];
  const float* wk = (const float*)d_in[5];
  const float* wv = (const float*)d_in[6];
  const float* wkip = (const float*)d_in[7];
  const float* wvip = (const float*)d_in[8];
  const float* wo = (const float*)d_in[9];
  const float* bo = (const float*)d_in[10];
  float* out = (float*)d_out;

  char* ws = (char*)d_ws;
  short* hsbf    = (short*)(ws + 0);          // 25165824 B (aliased by attnbuf)
  short* attnbuf = (short*)(ws + 0);          // reuse: hsbf dead after q_proj
  short* qbuf    = (short*)(ws + 25165824);   // 25165824
  short* kbuf    = (short*)(ws + 50331648);   //  3145728
  short* vtbuf   = (short*)(ws + 53477376);   //  3145728
  short* kipbuf  = (short*)(ws + 56623104);   //   393216
  short* vtipbuf = (short*)(ws + 57016320);   //   393216
  short* textbf  = (short*)(ws + 57409536);   //  3145728
  short* ipbf    = (short*)(ws + 60555264);   //   393216
  short* wqT     = (short*)(ws + 60948480);   //  4718592
  short* woT     = (short*)(ws + 65667072);   //  4718592
  short* wkvT    = (short*)(ws + 70385664);   //  2359296
  short* wkvipT  = (short*)(ws + 72744960);   //  2359296
  // total 75104256 bytes

  // --- pre-pass: convert/pack/transpose to bf16 ---
  conv_bf16_kernel<<<12288, 256, 0, stream>>>(hs, hsbf, 8192 * 1536 / 4);
  enc_pack_kernel<<<1728, 256, 0, stream>>>(enc, textbf, ipbf);
  transpose_conv_kernel<<<dim3(48, 48), 256, 0, stream>>>(wq, wqT, 1536, 1536, 0, 1536);
  transpose_conv_kernel<<<dim3(48, 48), 256, 0, stream>>>(wo, woT, 1536, 1536, 0, 1536);
  transpose_conv_kernel<<<dim3(24, 24), 256, 0, stream>>>(wk, wkvT, 768, 768, 0, 768);
  transpose_conv_kernel<<<dim3(24, 24), 256, 0, stream>>>(wv, wkvT, 768, 768, 768, 768);
  transpose_conv_kernel<<<dim3(24, 24), 256, 0, stream>>>(wkip, wkvipT, 768, 768, 0, 768);
  transpose_conv_kernel<<<dim3(24, 24), 256, 0, stream>>>(wvip, wkvipT, 768, 768, 768, 768);

  // --- projections ---
  q_proj_gemm<<<dim3(12, 64), 256, 0, stream>>>(hsbf, wqT, rc, rsn, qbuf);
  kv_gemm<<<dim3(12, 16), 256, 0, stream>>>(textbf, wkvT, kbuf, vtbuf, 9);
  kv_gemm<<<dim3(12, 2), 256, 0, stream>>>(ipbf, wkvipT, kipbuf, vtipbuf, 6);

  // --- attention ---
  attn_kernel<<<dim3(32, 24, 4), 256, 0, stream>>>(qbuf, kbuf, vtbuf, kipbuf,
                                                   vtipbuf, attnbuf);

  // --- output projection + bias + residual ---
  o_proj_gemm<<<dim3(12, 64), 256, 0, stream>>>(attnbuf, woT, bo, hs, out);
}

// Round 3
// 409.539 us; speedup vs baseline: 2.0031x; 1.0162x over previous
//
#include <hip/hip_runtime.h>
#include <hip/hip_bf16.h>

typedef __attribute__((ext_vector_type(8))) short short8;
typedef __attribute__((ext_vector_type(4))) short short4v;
typedef __attribute__((ext_vector_type(4))) float f32x4;

#define MFMA16(a, b, c) __builtin_amdgcn_mfma_f32_16x16x32_bf16(a, b, c, 0, 0, 0)

__device__ __forceinline__ short f2bf(float x) {
  union { float f; unsigned u; } v; v.f = x;
  unsigned u = v.u;
  u += 0x7FFFu + ((u >> 16) & 1u);  // RNE
  return (short)(u >> 16);
}

__device__ __forceinline__ void gload16(const void* g, void* l) {
  __builtin_amdgcn_global_load_lds(
      (const __attribute__((address_space(1))) unsigned int*)g,
      (__attribute__((address_space(3))) unsigned int*)l, 16, 0, 0);
}

// ---------------------------------------------------------------------------
// Pre-pass kernels: f32 -> bf16 convert / pack / transpose
// ---------------------------------------------------------------------------
__global__ __launch_bounds__(256) void conv_bf16_kernel(
    const float* __restrict__ in, short* __restrict__ out, int n4) {
  int i = blockIdx.x * 256 + threadIdx.x;
  if (i >= n4) return;
  f32x4 v = *(const f32x4*)(in + (size_t)i * 4);
  short4v s;
  s[0] = f2bf(v[0]); s[1] = f2bf(v[1]); s[2] = f2bf(v[2]); s[3] = f2bf(v[3]);
  *(short4v*)(out + (size_t)i * 4) = s;
}

// enc (4 x 576 x 768 f32) -> text_bf (4*512 x 768) + ip_bf (4*64 x 768)
__global__ __launch_bounds__(256) void enc_pack_kernel(
    const float* __restrict__ enc, short* __restrict__ text,
    short* __restrict__ ip) {
  int i4 = blockIdx.x * 256 + threadIdx.x;
  int i = i4 * 4;
  if (i >= 4 * 576 * 768) return;
  int c = i % 768;
  int rs = i / 768;
  int b = rs / 576, s = rs % 576;
  f32x4 v = *(const f32x4*)(enc + i);
  short4v o;
  o[0] = f2bf(v[0]); o[1] = f2bf(v[1]); o[2] = f2bf(v[2]); o[3] = f2bf(v[3]);
  if (s < 512)
    *(short4v*)(text + (size_t)(b * 512 + s) * 768 + c) = o;
  else
    *(short4v*)(ip + (size_t)(b * 64 + (s - 512)) * 768 + c) = o;
}

// in: K x N f32 row-major -> out: (N x K) bf16 row-major at row offset
__global__ __launch_bounds__(256) void transpose_conv_kernel(
    const float* __restrict__ in, short* __restrict__ out, int K, int N,
    int row_off, int out_ld) {
  __shared__ float tile[32][33];
  int c0 = blockIdx.x * 32, r0 = blockIdx.y * 32;
  int tx = threadIdx.x & 31, ty = threadIdx.x >> 5;  // ty 0..7
#pragma unroll
  for (int j = 0; j < 4; ++j)
    tile[ty + j * 8][tx] = in[(size_t)(r0 + ty + j * 8) * N + c0 + tx];
  __syncthreads();
#pragma unroll
  for (int j = 0; j < 4; ++j)
    out[(size_t)(row_off + c0 + ty + j * 8) * out_ld + r0 + tx] =
        f2bf(tile[tx][ty + j * 8]);
}

// ---------------------------------------------------------------------------
// Shared GEMM core: 128x128 tile, BK=64, global_load_lds + XOR swizzle (T2,
// both-sides per rule #21), 4 waves (2x2), 16x16x32 bf16 MFMA.
// ---------------------------------------------------------------------------
__device__ __forceinline__ void gemm_core(
    const short* __restrict__ A, const short* __restrict__ Bt, int K, int lda,
    int ldb, int row0, int col0, short* sA, short* sB, f32x4 acc[4][4]) {
  const int tid = threadIdx.x;
  const int lane = tid & 63;
  const int wid = tid >> 6;
  const int wr = (wid >> 1) * 64, wc = (wid & 1) * 64;
  const int lr = lane & 15;
  const int hk = (lane >> 4) * 16;   // byte offset of this lane's 8-elem group
  const int xr = (lr & 7) << 4;      // read-side XOR swizzle

  for (int kt = 0; kt < K; kt += 64) {
#pragma unroll
    for (int q = 0; q < 4; ++q) {
      int L = q * 4096 + tid * 16;           // linear LDS byte
      int r = L >> 7;                        // tile row (128B rows)
      int sb = (L & 127) ^ ((r & 7) << 4);   // inverse-swizzled source col byte
      int srcoff = kt + (sb >> 1);
      gload16(A + (size_t)(row0 + r) * lda + srcoff, (char*)sA + L);
      gload16(Bt + (size_t)(col0 + r) * ldb + srcoff, (char*)sB + L);
    }
    __syncthreads();
#pragma unroll
    for (int kk = 0; kk < 2; ++kk) {
      short8 af[4], bf[4];
#pragma unroll
      for (int m = 0; m < 4; ++m) {
        int row = wr + m * 16 + lr;
        af[m] = *(const short8*)((const char*)sA + row * 128 +
                                 ((kk * 64 + hk) ^ xr));
      }
#pragma unroll
      for (int n = 0; n < 4; ++n) {
        int row = wc + n * 16 + lr;
        bf[n] = *(const short8*)((const char*)sB + row * 128 +
                                 ((kk * 64 + hk) ^ xr));
      }
#pragma unroll
      for (int m = 0; m < 4; ++m)
#pragma unroll
        for (int n = 0; n < 4; ++n) acc[m][n] = MFMA16(af[m], bf[n], acc[m][n]);
    }
    __syncthreads();
  }
}

// ---------------------------------------------------------------------------
// Q projection GEMM + RoPE epilogue -> qbuf bf16 (B,H,S,64)
// ---------------------------------------------------------------------------
__global__ __launch_bounds__(256) void q_proj_gemm(
    const short* __restrict__ hsbf, const short* __restrict__ wqT,
    const float* __restrict__ rc, const float* __restrict__ rsn,
    short* __restrict__ qbuf) {
  __shared__ short sA[128 * 64];
  __shared__ short sB[128 * 64];
  f32x4 acc[4][4] = {};
  const int row0 = blockIdx.y * 128, col0 = blockIdx.x * 128;
  gemm_core(hsbf, wqT, 1536, 1536, 1536, row0, col0, sA, sB, acc);

  const int tid = threadIdx.x;
  const int lane = tid & 63, wid = tid >> 6;
  const int wr = (wid >> 1) * 64, wc = (wid & 1) * 64;
  const int lr = lane & 15, lrow4 = (lane >> 4) * 4;
  const int h = (col0 + wc) >> 6;
#pragma unroll
  for (int m = 0; m < 4; ++m) {
#pragma unroll
    for (int r = 0; r < 4; ++r) {
      int grow = row0 + wr + m * 16 + lrow4 + r;
      int b = grow >> 11, t = grow & 2047;
      float v0 = acc[m][0][r], v1 = acc[m][1][r];
      float c0 = rc[t * 32 + lr], s0 = rsn[t * 32 + lr];
      float c1 = rc[t * 32 + 16 + lr], s1 = rsn[t * 32 + 16 + lr];
      float n0 = v0 * c0 - v1 * s0;
      float n1 = v1 * c1 + v0 * s1;
      short* ob = qbuf + ((size_t)(b * 24 + h) * 2048 + t) * 64;
      ob[lr] = f2bf(n0);
      ob[16 + lr] = f2bf(n1);
      ob[32 + lr] = f2bf(acc[m][2][r]);
      ob[48 + lr] = f2bf(acc[m][3][r]);
    }
  }
}

// ---------------------------------------------------------------------------
// Fused K|V projection GEMM (B^T = [wkT ; wvT], N=1536).
// ---------------------------------------------------------------------------
__global__ __launch_bounds__(256) void kv_gemm(
    const short* __restrict__ Abf, const short* __restrict__ wkvT,
    short* __restrict__ kout, short* __restrict__ vtout, int rlog2) {
  __shared__ short sA[128 * 64];
  __shared__ short sB[128 * 64];
  f32x4 acc[4][4] = {};
  const int row0 = blockIdx.y * 128, col0 = blockIdx.x * 128;
  gemm_core(Abf, wkvT, 768, 768, 768, row0, col0, sA, sB, acc);

  const int tid = threadIdx.x;
  const int lane = tid & 63, wid = tid >> 6;
  const int wr = (wid >> 1) * 64, wc = (wid & 1) * 64;
  const int lr = lane & 15, lrow4 = (lane >> 4) * 4;
  const int rmask = (1 << rlog2) - 1;
#pragma unroll
  for (int m = 0; m < 4; ++m) {
#pragma unroll
    for (int n = 0; n < 4; ++n) {
#pragma unroll
      for (int r = 0; r < 4; ++r) {
        int grow = row0 + wr + m * 16 + lrow4 + r;
        int gcol = col0 + wc + n * 16 + lr;
        int b = grow >> rlog2, key = grow & rmask;
        short val = f2bf(acc[m][n][r]);
        if (gcol < 768) {
          int kvh = gcol >> 6, d = gcol & 63;
          kout[((((size_t)(b * 12 + kvh)) << rlog2) + key) * 64 + d] = val;
        } else {
          int c2 = gcol - 768;
          int kvh = c2 >> 6, d = c2 & 63;
          vtout[(((size_t)((b * 12 + kvh) * 64 + d)) << rlog2) + key] = val;
        }
      }
    }
  }
}

// ---------------------------------------------------------------------------
// Output projection GEMM + bias + residual -> f32
// ---------------------------------------------------------------------------
__global__ __launch_bounds__(256) void o_proj_gemm(
    const short* __restrict__ attnbf, const short* __restrict__ woT,
    const float* __restrict__ bo, const float* __restrict__ resid,
    float* __restrict__ out) {
  __shared__ short sA[128 * 64];
  __shared__ short sB[128 * 64];
  f32x4 acc[4][4] = {};
  const int row0 = blockIdx.y * 128, col0 = blockIdx.x * 128;
  gemm_core(attnbf, woT, 1536, 1536, 1536, row0, col0, sA, sB, acc);

  const int tid = threadIdx.x;
  const int lane = tid & 63, wid = tid >> 6;
  const int wr = (wid >> 1) * 64, wc = (wid & 1) * 64;
  const int lr = lane & 15, lrow4 = (lane >> 4) * 4;
#pragma unroll
  for (int m = 0; m < 4; ++m) {
#pragma unroll
    for (int n = 0; n < 4; ++n) {
#pragma unroll
      for (int r = 0; r < 4; ++r) {
        int grow = row0 + wr + m * 16 + lrow4 + r;
        int gcol = col0 + wc + n * 16 + lr;
        size_t off = (size_t)grow * 1536 + gcol;
        out[off] = acc[m][n][r] + bo[gcol] + resid[off];
      }
    }
  }
}

// ---------------------------------------------------------------------------
// Attention: block = (b, h, 64 q rows), 4 waves x 16 rows.
// No __syncthreads (sP slices are per-wave); K-tile loop fully unrolled so
// the compiler software-pipelines loads across tiles. exp2-domain softmax.
// ---------------------------------------------------------------------------
#define QK_SCALE_LOG2E 0.18033688011112042f  // (1/8) * log2(e)

template <int NKF, int KSPV, int NT>
__device__ __forceinline__ void attn_pass(
    const short* __restrict__ kp, const short* __restrict__ vp, int vstride,
    const short8 qf[2], short (*sP)[136],
    float m_run[4], float l_run[4], f32x4 o_acc[4], int lane) {
  const int lr = lane & 15, lk = (lane >> 4) * 8, lrow4 = (lane >> 4) * 4;
#pragma unroll
  for (int kt = 0; kt < NT; ++kt) {
    f32x4 s[NKF];
#pragma unroll
    for (int nf = 0; nf < NKF; ++nf) {
      const short* kb = kp + (size_t)(kt * (NKF * 16) + nf * 16 + lr) * 64 + lk;
      short8 k0 = *(const short8*)kb;
      short8 k1 = *(const short8*)(kb + 32);
      f32x4 a = {0.f, 0.f, 0.f, 0.f};
      a = MFMA16(qf[0], k0, a);
      a = MFMA16(qf[1], k1, a);
      s[nf] = a;
    }
#pragma unroll
    for (int r = 0; r < 4; ++r) {
#pragma unroll
      for (int nf = 0; nf < NKF; ++nf) s[nf][r] *= QK_SCALE_LOG2E;
      float mx = s[0][r];
#pragma unroll
      for (int nf = 1; nf < NKF; ++nf) mx = fmaxf(mx, s[nf][r]);
      mx = fmaxf(mx, __shfl_xor(mx, 1));
      mx = fmaxf(mx, __shfl_xor(mx, 2));
      mx = fmaxf(mx, __shfl_xor(mx, 4));
      mx = fmaxf(mx, __shfl_xor(mx, 8));
      float mn = fmaxf(m_run[r], mx);
      float corr = __builtin_amdgcn_exp2f(m_run[r] - mn);
      m_run[r] = mn;
      float rs = 0.f;
#pragma unroll
      for (int nf = 0; nf < NKF; ++nf) {
        float p = __builtin_amdgcn_exp2f(s[nf][r] - mn);
        s[nf][r] = p;
        rs += p;
      }
      rs += __shfl_xor(rs, 1);
      rs += __shfl_xor(rs, 2);
      rs += __shfl_xor(rs, 4);
      rs += __shfl_xor(rs, 8);
      l_run[r] = l_run[r] * corr + rs;
#pragma unroll
      for (int no = 0; no < 4; ++no) o_acc[no][r] *= corr;
    }
#pragma unroll
    for (int nf = 0; nf < NKF; ++nf)
#pragma unroll
      for (int r = 0; r < 4; ++r) sP[lrow4 + r][nf * 16 + lr] = f2bf(s[nf][r]);
    // no barrier: sP slice is private to this wave; compiler inserts lgkm waits
#pragma unroll
    for (int ks = 0; ks < KSPV; ++ks) {
      short8 pa = *(const short8*)&sP[lr][ks * 32 + lk];
#pragma unroll
      for (int no = 0; no < 4; ++no) {
        const short* vb =
            vp + (size_t)(no * 16 + lr) * vstride + kt * (NKF * 16) + ks * 32 + lk;
        short8 vf = *(const short8*)vb;
        o_acc[no] = MFMA16(pa, vf, o_acc[no]);
      }
    }
  }
}

__global__ __launch_bounds__(256, 4) void attn_kernel(
    const short* __restrict__ qbuf, const short* __restrict__ kbuf,
    const short* __restrict__ vtbuf, const short* __restrict__ kipbuf,
    const short* __restrict__ vtipbuf, short* __restrict__ attn_out) {
  const int tid = threadIdx.x;
  const int lane = tid & 63, wid = tid >> 6;
  // bijective XCD swizzle: 3072 blocks, 8 XCDs, 384 contiguous per XCD
  const int f = (blockIdx.x & 7) * 384 + (blockIdx.x >> 3);
  const int qt = f & 31;          // 0..31
  const int h = (f >> 5) % 24;    // 0..23
  const int b = f / (32 * 24);    // 0..3
  const int kvh = h >> 1;
  const int lr = lane & 15, lk = (lane >> 4) * 8, lrow4 = (lane >> 4) * 4;

  __shared__ short sPall[4][16][136];
  short(*sP)[136] = sPall[wid];

  const short* qp = qbuf + (size_t)(b * 24 + h) * 2048 * 64;
  const short* kp = kbuf + (size_t)(b * 12 + kvh) * 512 * 64;
  const short* vp = vtbuf + (size_t)(b * 12 + kvh) * 64 * 512;
  const short* kip = kipbuf + (size_t)(b * 12 + kvh) * 64 * 64;
  const short* vip = vtipbuf + (size_t)(b * 12 + kvh) * 64 * 64;

  const int q0 = qt * 64 + wid * 16;
  short8 qf[2];
  qf[0] = *(const short8*)(qp + (size_t)(q0 + lr) * 64 + lk);
  qf[1] = *(const short8*)(qp + (size_t)(q0 + lr) * 64 + 32 + lk);

  float m_run[4] = {-3.0e38f, -3.0e38f, -3.0e38f, -3.0e38f};
  float l_run[4] = {0.f, 0.f, 0.f, 0.f};
  f32x4 o_acc[4] = {};

  attn_pass<8, 4, 4>(kp, vp, 512, qf, sP, m_run, l_run, o_acc, lane);

  float o_fin[4][4];
#pragma unroll
  for (int r = 0; r < 4; ++r) {
    float inv = 1.0f / l_run[r];
#pragma unroll
    for (int no = 0; no < 4; ++no) o_fin[no][r] = o_acc[no][r] * inv;
    m_run[r] = -3.0e38f;
    l_run[r] = 0.f;
  }
#pragma unroll
  for (int no = 0; no < 4; ++no) o_acc[no] = f32x4{0.f, 0.f, 0.f, 0.f};

  attn_pass<4, 2, 1>(kip, vip, 64, qf, sP, m_run, l_run, o_acc, lane);

#pragma unroll
  for (int r = 0; r < 4; ++r) {
    float inv = 1.0f / l_run[r];
    int grow = b * 2048 + q0 + lrow4 + r;
#pragma unroll
    for (int no = 0; no < 4; ++no) {
      float val = o_fin[no][r] + o_acc[no][r] * inv;  // IP_SCALE = 1
      attn_out[(size_t)grow * 1536 + h * 64 + no * 16 + lr] = f2bf(val);
    }
  }
}

// ---------------------------------------------------------------------------
extern "C" void kernel_launch(void* const* d_in, const int* in_sizes, int n_in,
                              void* d_out, int out_size, void* d_ws, size_t ws_size,
                              hipStream_t stream) {
  const float* hs = (const float*)d_in[0];
  const float* enc = (const float*)d_in[1];
  const float* rc = (const float*)d_in[2];
  const float* rsn = (const float*)d_in[3];
  const float* wq = (const float*)d_in[4];
  const float* wk = (const float*)d_in[5];
  const float* wv = (const float*)d_in[6];
  const float* wkip = (const float*)d_in[7];
  const float* wvip = (const float*)d_in[8];
  const float* wo = (const float*)d_in[9];
  const float* bo = (const float*)d_in[10];
  float* out = (float*)d_out;

  char* ws = (char*)d_ws;
  short* hsbf    = (short*)(ws + 0);          // 25165824 B (aliased by attnbuf)
  short* attnbuf = (short*)(ws + 0);          // reuse: hsbf dead after q_proj
  short* qbuf    = (short*)(ws + 25165824);   // 25165824
  short* kbuf    = (short*)(ws + 50331648);   //  3145728
  short* vtbuf   = (short*)(ws + 53477376);   //  3145728
  short* kipbuf  = (short*)(ws + 56623104);   //   393216
  short* vtipbuf = (short*)(ws + 57016320);   //   393216
  short* textbf  = (short*)(ws + 57409536);   //  3145728
  short* ipbf    = (short*)(ws + 60555264);   //   393216
  short* wqT     = (short*)(ws + 60948480);   //  4718592
  short* woT     = (short*)(ws + 65667072);   //  4718592
  short* wkvT    = (short*)(ws + 70385664);   //  2359296
  short* wkvipT  = (short*)(ws + 72744960);   //  2359296
  // total 75104256 bytes

  // --- pre-pass: convert/pack/transpose to bf16 ---
  conv_bf16_kernel<<<12288, 256, 0, stream>>>(hs, hsbf, 8192 * 1536 / 4);
  enc_pack_kernel<<<1728, 256, 0, stream>>>(enc, textbf, ipbf);
  transpose_conv_kernel<<<dim3(48, 48), 256, 0, stream>>>(wq, wqT, 1536, 1536, 0, 1536);
  transpose_conv_kernel<<<dim3(48, 48), 256, 0, stream>>>(wo, woT, 1536, 1536, 0, 1536);
  transpose_conv_kernel<<<dim3(24, 24), 256, 0, stream>>>(wk, wkvT, 768, 768, 0, 768);
  transpose_conv_kernel<<<dim3(24, 24), 256, 0, stream>>>(wv, wkvT, 768, 768, 768, 768);
  transpose_conv_kernel<<<dim3(24, 24), 256, 0, stream>>>(wkip, wkvipT, 768, 768, 0, 768);
  transpose_conv_kernel<<<dim3(24, 24), 256, 0, stream>>>(wvip, wkvipT, 768, 768, 768, 768);

  // --- projections ---
  q_proj_gemm<<<dim3(12, 64), 256, 0, stream>>>(hsbf, wqT, rc, rsn, qbuf);
  kv_gemm<<<dim3(12, 16), 256, 0, stream>>>(textbf, wkvT, kbuf, vtbuf, 9);
  kv_gemm<<<dim3(12, 2), 256, 0, stream>>>(ipbf, wkvipT, kipbuf, vtipbuf, 6);

  // --- attention ---
  attn_kernel<<<3072, 256, 0, stream>>>(qbuf, kbuf, vtbuf, kipbuf,
                                        vtipbuf, attnbuf);

  // --- output projection + bias + residual ---
  o_proj_gemm<<<dim3(12, 64), 256, 0, stream>>>(attnbuf, woT, bo, hs, out);
}

// Round 4
// 272.473 us; speedup vs baseline: 3.0108x; 1.5030x over previous
//
#include <hip/hip_runtime.h>
#include <hip/hip_bf16.h>

typedef __attribute__((ext_vector_type(8))) short short8;
typedef __attribute__((ext_vector_type(4))) short short4v;
typedef __attribute__((ext_vector_type(4))) float f32x4;

#define MFMA16(a, b, c) __builtin_amdgcn_mfma_f32_16x16x32_bf16(a, b, c, 0, 0, 0)
#define QK_SCALE_LOG2E 0.18033688011112042f  // (1/8) * log2(e)

__device__ __forceinline__ short f2bf(float x) {
  union { float f; unsigned u; } v; v.f = x;
  unsigned u = v.u;
  u += 0x7FFFu + ((u >> 16) & 1u);  // RNE
  return (short)(u >> 16);
}

__device__ __forceinline__ void gload16(const void* g, void* l) {
  __builtin_amdgcn_global_load_lds(
      (const __attribute__((address_space(1))) unsigned int*)g,
      (__attribute__((address_space(3))) unsigned int*)l, 16, 0, 0);
}

// ---------------------------------------------------------------------------
// Pre-pass kernels: f32 -> bf16 convert / pack / transpose
// ---------------------------------------------------------------------------
__global__ __launch_bounds__(256) void conv_bf16_kernel(
    const float* __restrict__ in, short* __restrict__ out, int n4) {
  int i = blockIdx.x * 256 + threadIdx.x;
  if (i >= n4) return;
  f32x4 v = *(const f32x4*)(in + (size_t)i * 4);
  short4v s;
  s[0] = f2bf(v[0]); s[1] = f2bf(v[1]); s[2] = f2bf(v[2]); s[3] = f2bf(v[3]);
  *(short4v*)(out + (size_t)i * 4) = s;
}

// enc (4 x 576 x 768 f32) -> text_bf (4*512 x 768) + ip_bf (4*64 x 768)
__global__ __launch_bounds__(256) void enc_pack_kernel(
    const float* __restrict__ enc, short* __restrict__ text,
    short* __restrict__ ip) {
  int i4 = blockIdx.x * 256 + threadIdx.x;
  int i = i4 * 4;
  if (i >= 4 * 576 * 768) return;
  int c = i % 768;
  int rs = i / 768;
  int b = rs / 576, s = rs % 576;
  f32x4 v = *(const f32x4*)(enc + i);
  short4v o;
  o[0] = f2bf(v[0]); o[1] = f2bf(v[1]); o[2] = f2bf(v[2]); o[3] = f2bf(v[3]);
  if (s < 512)
    *(short4v*)(text + (size_t)(b * 512 + s) * 768 + c) = o;
  else
    *(short4v*)(ip + (size_t)(b * 64 + (s - 512)) * 768 + c) = o;
}

// in: K x N f32 row-major -> out: (N x K) bf16 row-major at row offset
__global__ __launch_bounds__(256) void transpose_conv_kernel(
    const float* __restrict__ in, short* __restrict__ out, int K, int N,
    int row_off, int out_ld) {
  __shared__ float tile[32][33];
  int c0 = blockIdx.x * 32, r0 = blockIdx.y * 32;
  int tx = threadIdx.x & 31, ty = threadIdx.x >> 5;  // ty 0..7
#pragma unroll
  for (int j = 0; j < 4; ++j)
    tile[ty + j * 8][tx] = in[(size_t)(r0 + ty + j * 8) * N + c0 + tx];
  __syncthreads();
#pragma unroll
  for (int j = 0; j < 4; ++j)
    out[(size_t)(row_off + c0 + ty + j * 8) * out_ld + r0 + tx] =
        f2bf(tile[tx][ty + j * 8]);
}

// ---------------------------------------------------------------------------
// Shared GEMM core: 128x128 tile, BK=64, global_load_lds + XOR swizzle.
// ---------------------------------------------------------------------------
__device__ __forceinline__ void gemm_core(
    const short* __restrict__ A, const short* __restrict__ Bt, int K, int lda,
    int ldb, int row0, int col0, short* sA, short* sB, f32x4 acc[4][4]) {
  const int tid = threadIdx.x;
  const int lane = tid & 63;
  const int wid = tid >> 6;
  const int wr = (wid >> 1) * 64, wc = (wid & 1) * 64;
  const int lr = lane & 15;
  const int hk = (lane >> 4) * 16;   // byte offset of this lane's 8-elem group
  const int xr = (lr & 7) << 4;      // read-side XOR swizzle

  for (int kt = 0; kt < K; kt += 64) {
#pragma unroll
    for (int q = 0; q < 4; ++q) {
      int L = q * 4096 + tid * 16;           // linear LDS byte
      int r = L >> 7;                        // tile row (128B rows)
      int sb = (L & 127) ^ ((r & 7) << 4);   // inverse-swizzled source col byte
      int srcoff = kt + (sb >> 1);
      gload16(A + (size_t)(row0 + r) * lda + srcoff, (char*)sA + L);
      gload16(Bt + (size_t)(col0 + r) * ldb + srcoff, (char*)sB + L);
    }
    __syncthreads();
#pragma unroll
    for (int kk = 0; kk < 2; ++kk) {
      short8 af[4], bf[4];
#pragma unroll
      for (int m = 0; m < 4; ++m) {
        int row = wr + m * 16 + lr;
        af[m] = *(const short8*)((const char*)sA + row * 128 +
                                 ((kk * 64 + hk) ^ xr));
      }
#pragma unroll
      for (int n = 0; n < 4; ++n) {
        int row = wc + n * 16 + lr;
        bf[n] = *(const short8*)((const char*)sB + row * 128 +
                                 ((kk * 64 + hk) ^ xr));
      }
#pragma unroll
      for (int m = 0; m < 4; ++m)
#pragma unroll
        for (int n = 0; n < 4; ++n) acc[m][n] = MFMA16(af[m], bf[n], acc[m][n]);
    }
    __syncthreads();
  }
}

// ---------------------------------------------------------------------------
// Q projection GEMM + RoPE + pre-scale by SCALE*log2(e) -> qbuf bf16 (B,H,S,64)
// ---------------------------------------------------------------------------
__global__ __launch_bounds__(256) void q_proj_gemm(
    const short* __restrict__ hsbf, const short* __restrict__ wqT,
    const float* __restrict__ rc, const float* __restrict__ rsn,
    short* __restrict__ qbuf) {
  __shared__ short sA[128 * 64];
  __shared__ short sB[128 * 64];
  f32x4 acc[4][4] = {};
  const int row0 = blockIdx.y * 128, col0 = blockIdx.x * 128;
  gemm_core(hsbf, wqT, 1536, 1536, 1536, row0, col0, sA, sB, acc);

  const int tid = threadIdx.x;
  const int lane = tid & 63, wid = tid >> 6;
  const int wr = (wid >> 1) * 64, wc = (wid & 1) * 64;
  const int lr = lane & 15, lrow4 = (lane >> 4) * 4;
  const int h = (col0 + wc) >> 6;
#pragma unroll
  for (int m = 0; m < 4; ++m) {
#pragma unroll
    for (int r = 0; r < 4; ++r) {
      int grow = row0 + wr + m * 16 + lrow4 + r;
      int b = grow >> 11, t = grow & 2047;
      float v0 = acc[m][0][r], v1 = acc[m][1][r];
      float c0 = rc[t * 32 + lr], s0 = rsn[t * 32 + lr];
      float c1 = rc[t * 32 + 16 + lr], s1 = rsn[t * 32 + 16 + lr];
      float n0 = (v0 * c0 - v1 * s0) * QK_SCALE_LOG2E;
      float n1 = (v1 * c1 + v0 * s1) * QK_SCALE_LOG2E;
      short* ob = qbuf + ((size_t)(b * 24 + h) * 2048 + t) * 64;
      ob[lr] = f2bf(n0);
      ob[16 + lr] = f2bf(n1);
      ob[32 + lr] = f2bf(acc[m][2][r] * QK_SCALE_LOG2E);
      ob[48 + lr] = f2bf(acc[m][3][r] * QK_SCALE_LOG2E);
    }
  }
}

// ---------------------------------------------------------------------------
// Fused K|V projection GEMM (B^T = [wkT ; wvT], N=1536).
// ---------------------------------------------------------------------------
__global__ __launch_bounds__(256) void kv_gemm(
    const short* __restrict__ Abf, const short* __restrict__ wkvT,
    short* __restrict__ kout, short* __restrict__ vtout, int rlog2) {
  __shared__ short sA[128 * 64];
  __shared__ short sB[128 * 64];
  f32x4 acc[4][4] = {};
  const int row0 = blockIdx.y * 128, col0 = blockIdx.x * 128;
  gemm_core(Abf, wkvT, 768, 768, 768, row0, col0, sA, sB, acc);

  const int tid = threadIdx.x;
  const int lane = tid & 63, wid = tid >> 6;
  const int wr = (wid >> 1) * 64, wc = (wid & 1) * 64;
  const int lr = lane & 15, lrow4 = (lane >> 4) * 4;
  const int rmask = (1 << rlog2) - 1;
#pragma unroll
  for (int m = 0; m < 4; ++m) {
#pragma unroll
    for (int n = 0; n < 4; ++n) {
#pragma unroll
      for (int r = 0; r < 4; ++r) {
        int grow = row0 + wr + m * 16 + lrow4 + r;
        int gcol = col0 + wc + n * 16 + lr;
        int b = grow >> rlog2, key = grow & rmask;
        short val = f2bf(acc[m][n][r]);
        if (gcol < 768) {
          int kvh = gcol >> 6, d = gcol & 63;
          kout[((((size_t)(b * 12 + kvh)) << rlog2) + key) * 64 + d] = val;
        } else {
          int c2 = gcol - 768;
          int kvh = c2 >> 6, d = c2 & 63;
          vtout[(((size_t)((b * 12 + kvh) * 64 + d)) << rlog2) + key] = val;
        }
      }
    }
  }
}

// ---------------------------------------------------------------------------
// Output projection GEMM + bias + residual -> f32
// ---------------------------------------------------------------------------
__global__ __launch_bounds__(256) void o_proj_gemm(
    const short* __restrict__ attnbf, const short* __restrict__ woT,
    const float* __restrict__ bo, const float* __restrict__ resid,
    float* __restrict__ out) {
  __shared__ short sA[128 * 64];
  __shared__ short sB[128 * 64];
  f32x4 acc[4][4] = {};
  const int row0 = blockIdx.y * 128, col0 = blockIdx.x * 128;
  gemm_core(attnbf, woT, 1536, 1536, 1536, row0, col0, sA, sB, acc);

  const int tid = threadIdx.x;
  const int lane = tid & 63, wid = tid >> 6;
  const int wr = (wid >> 1) * 64, wc = (wid & 1) * 64;
  const int lr = lane & 15, lrow4 = (lane >> 4) * 4;
#pragma unroll
  for (int m = 0; m < 4; ++m) {
#pragma unroll
    for (int n = 0; n < 4; ++n) {
#pragma unroll
      for (int r = 0; r < 4; ++r) {
        int grow = row0 + wr + m * 16 + lrow4 + r;
        int gcol = col0 + wc + n * 16 + lr;
        size_t off = (size_t)grow * 1536 + gcol;
        out[off] = acc[m][n][r] + bo[gcol] + resid[off];
      }
    }
  }
}

// ---------------------------------------------------------------------------
// Attention: block = (b, h, 64 q rows), 4 waves x 16 q-rows.
// Swapped QK^T (mfma(K,Q)) -> per-lane key-local softmax (2 shfl per reduce).
// K/V^T staged in LDS (KVBLK=64, double-buffered, 2-phase prefetch pipeline,
// both-sides XOR swizzle). Text = tiles 0..7, ip = tile 8 (own m/l/O state).
// Q is pre-scaled by SCALE*log2(e); softmax runs in exp2 domain.
// ---------------------------------------------------------------------------
__device__ __forceinline__ void stage_tile(const short* __restrict__ ks,
                                           const short* __restrict__ vs,
                                           int vstr, short* kb, short* vb,
                                           int tid) {
#pragma unroll
  for (int q = 0; q < 2; ++q) {
    int L = q * 4096 + tid * 16;            // LDS byte (linear dest)
    int row = L >> 7;                       // 0..63
    int sc = ((L & 127) ^ ((row & 7) << 4)) >> 1;  // inverse-swz src col
    gload16(ks + row * 64 + sc, (char*)kb + L);
    gload16(vs + (size_t)row * vstr + sc, (char*)vb + L);
  }
}

__device__ __forceinline__ void attn_tile(const short* kb, const short* vb,
                                          short (*sP)[72], const short8 qf[2],
                                          float& m_run, float& l_run,
                                          f32x4 o_acc[4], int lane) {
  const int lr = lane & 15, hi = lane >> 4;
  // ---- QK^T (swapped: A=K rows, B=Q rows) ----
  f32x4 s[4];
#pragma unroll
  for (int nf = 0; nf < 4; ++nf) {
    int row = nf * 16 + lr;
    int rx = (row & 7) << 4;
    const char* base = (const char*)kb + row * 128;
    short8 k0 = *(const short8*)(base + ((hi * 16) ^ rx));
    short8 k1 = *(const short8*)(base + ((64 + hi * 16) ^ rx));
    f32x4 a = {0.f, 0.f, 0.f, 0.f};
    a = MFMA16(k0, qf[0], a);
    a = MFMA16(k1, qf[1], a);
    s[nf] = a;  // s[nf][r]: key = nf*16 + hi*4 + r, q = lr (log2 domain)
  }
  // ---- in-register key-reduce max (15 fmax + 2 shfl) ----
  float mx = s[0][0];
#pragma unroll
  for (int nf = 0; nf < 4; ++nf)
#pragma unroll
    for (int r = 0; r < 4; ++r) mx = fmaxf(mx, s[nf][r]);
  mx = fmaxf(mx, __shfl_xor(mx, 16));
  mx = fmaxf(mx, __shfl_xor(mx, 32));
  // ---- defer-max rescale (wave-uniform gate, THR=8 in log2 domain) ----
  if (__any(mx - m_run > 8.0f)) {
    float mn = fmaxf(m_run, mx);
    float corr = __builtin_amdgcn_exp2f(m_run - mn);
    m_run = mn;
    l_run *= corr;
#pragma unroll
    for (int r = 0; r < 4; ++r) {
      float cr = __shfl(corr, hi * 4 + r);  // corr for o_acc row q = hi*4+r
#pragma unroll
      for (int no = 0; no < 4; ++no) o_acc[no][r] *= cr;
    }
  }
  // ---- exp + sum (in-register + 2 shfl) + P write ----
  float rs = 0.f;
#pragma unroll
  for (int nf = 0; nf < 4; ++nf) {
    short4v pk;
#pragma unroll
    for (int r = 0; r < 4; ++r) {
      float p = __builtin_amdgcn_exp2f(s[nf][r] - m_run);
      rs += p;
      pk[r] = f2bf(p);
    }
    *(short4v*)&sP[lr][nf * 16 + hi * 4] = pk;  // keys nf*16+hi*4..+3, q=lr
  }
  rs += __shfl_xor(rs, 16);
  rs += __shfl_xor(rs, 32);
  l_run += rs;
  // ---- PV: A = P[q][key] from sP, B = V^T[d][key] from LDS ----
#pragma unroll
  for (int ks = 0; ks < 2; ++ks) {
    short8 pa = *(const short8*)&sP[lr][ks * 32 + hi * 8];
#pragma unroll
    for (int no = 0; no < 4; ++no) {
      int row = no * 16 + lr;
      int rx = (row & 7) << 4;
      short8 vf = *(const short8*)((const char*)vb + row * 128 +
                                   ((ks * 64 + hi * 16) ^ rx));
      o_acc[no] = MFMA16(pa, vf, o_acc[no]);
    }
  }
}

__global__ __launch_bounds__(256, 3) void attn_kernel(
    const short* __restrict__ qbuf, const short* __restrict__ kbuf,
    const short* __restrict__ vtbuf, const short* __restrict__ kipbuf,
    const short* __restrict__ vtipbuf, short* __restrict__ attn_out) {
  const int tid = threadIdx.x;
  const int lane = tid & 63, wid = tid >> 6;
  // bijective XCD swizzle: 3072 blocks, 8 XCDs, 384 contiguous per XCD
  const int f = (blockIdx.x & 7) * 384 + (blockIdx.x >> 3);
  const int qt = f & 31;
  const int h = (f >> 5) % 24;
  const int b = f / (32 * 24);
  const int kvh = h >> 1;
  const int lr = lane & 15, hi = lane >> 4;

  __shared__ short skv_k[2 * 64 * 64];   // K tiles [buf][key][d]   (swizzled)
  __shared__ short skv_v[2 * 64 * 64];   // V^T tiles [buf][d][key] (swizzled)
  __shared__ short sPall[4][16][72];
  short(*sP)[72] = sPall[wid];

  const short* qp = qbuf + (size_t)(b * 24 + h) * 2048 * 64;
  const short* kp = kbuf + (size_t)(b * 12 + kvh) * 512 * 64;
  const short* vp = vtbuf + (size_t)(b * 12 + kvh) * 64 * 512;
  const short* kip = kipbuf + (size_t)(b * 12 + kvh) * 64 * 64;
  const short* vip = vtipbuf + (size_t)(b * 12 + kvh) * 64 * 64;

  const int q0 = qt * 64 + wid * 16;
  short8 qf[2];
  qf[0] = *(const short8*)(qp + (size_t)(q0 + lr) * 64 + hi * 8);
  qf[1] = *(const short8*)(qp + (size_t)(q0 + lr) * 64 + 32 + hi * 8);

  float m1 = -1.0e30f, l1 = 0.f, m2 = -1.0e30f, l2 = 0.f;
  f32x4 oacc1[4] = {}, oacc2[4] = {};

  // prologue: stage tile 0
  stage_tile(kp, vp, 512, skv_k, skv_v, tid);
  __syncthreads();

  for (int t = 0; t < 9; ++t) {
    int cur = t & 1, nxt = cur ^ 1;
    if (t < 8) {
      const short* ks_ = (t < 7) ? kp + (t + 1) * 64 * 64 : kip;
      const short* vs_ = (t < 7) ? vp + (t + 1) * 64 : vip;
      int vstr = (t < 7) ? 512 : 64;
      stage_tile(ks_, vs_, vstr, skv_k + nxt * 4096, skv_v + nxt * 4096, tid);
    }
    if (t < 8)
      attn_tile(skv_k + cur * 4096, skv_v + cur * 4096, sP, qf, m1, l1, oacc1, lane);
    else
      attn_tile(skv_k + cur * 4096, skv_v + cur * 4096, sP, qf, m2, l2, oacc2, lane);
    __syncthreads();  // drains vmcnt (next tile staged) + LDS reuse safety
  }

  float inv1 = 1.0f / l1, inv2 = 1.0f / l2;
#pragma unroll
  for (int r = 0; r < 4; ++r) {
    float i1 = __shfl(inv1, hi * 4 + r);
    float i2 = __shfl(inv2, hi * 4 + r);
    int grow = b * 2048 + q0 + hi * 4 + r;
#pragma unroll
    for (int no = 0; no < 4; ++no) {
      float val = oacc1[no][r] * i1 + oacc2[no][r] * i2;  // IP_SCALE = 1
      attn_out[(size_t)grow * 1536 + h * 64 + no * 16 + lr] = f2bf(val);
    }
  }
}

// ---------------------------------------------------------------------------
extern "C" void kernel_launch(void* const* d_in, const int* in_sizes, int n_in,
                              void* d_out, int out_size, void* d_ws, size_t ws_size,
                              hipStream_t stream) {
  const float* hs = (const float*)d_in[0];
  const float* enc = (const float*)d_in[1];
  const float* rc = (const float*)d_in[2];
  const float* rsn = (const float*)d_in[3];
  const float* wq = (const float*)d_in[4];
  const float* wk = (const float*)d_in[5];
  const float* wv = (const float*)d_in[6];
  const float* wkip = (const float*)d_in[7];
  const float* wvip = (const float*)d_in[8];
  const float* wo = (const float*)d_in[9];
  const float* bo = (const float*)d_in[10];
  float* out = (float*)d_out;

  char* ws = (char*)d_ws;
  short* hsbf    = (short*)(ws + 0);          // 25165824 B (aliased by attnbuf)
  short* attnbuf = (short*)(ws + 0);          // reuse: hsbf dead after q_proj
  short* qbuf    = (short*)(ws + 25165824);   // 25165824
  short* kbuf    = (short*)(ws + 50331648);   //  3145728
  short* vtbuf   = (short*)(ws + 53477376);   //  3145728
  short* kipbuf  = (short*)(ws + 56623104);   //   393216
  short* vtipbuf = (short*)(ws + 57016320);   //   393216
  short* textbf  = (short*)(ws + 57409536);   //  3145728
  short* ipbf    = (short*)(ws + 60555264);   //   393216
  short* wqT     = (short*)(ws + 60948480);   //  4718592
  short* woT     = (short*)(ws + 65667072);   //  4718592
  short* wkvT    = (short*)(ws + 70385664);   //  2359296
  short* wkvipT  = (short*)(ws + 72744960);   //  2359296
  // total 75104256 bytes

  // --- pre-pass: convert/pack/transpose to bf16 ---
  conv_bf16_kernel<<<12288, 256, 0, stream>>>(hs, hsbf, 8192 * 1536 / 4);
  enc_pack_kernel<<<1728, 256, 0, stream>>>(enc, textbf, ipbf);
  transpose_conv_kernel<<<dim3(48, 48), 256, 0, stream>>>(wq, wqT, 1536, 1536, 0, 1536);
  transpose_conv_kernel<<<dim3(48, 48), 256, 0, stream>>>(wo, woT, 1536, 1536, 0, 1536);
  transpose_conv_kernel<<<dim3(24, 24), 256, 0, stream>>>(wk, wkvT, 768, 768, 0, 768);
  transpose_conv_kernel<<<dim3(24, 24), 256, 0, stream>>>(wv, wkvT, 768, 768, 768, 768);
  transpose_conv_kernel<<<dim3(24, 24), 256, 0, stream>>>(wkip, wkvipT, 768, 768, 0, 768);
  transpose_conv_kernel<<<dim3(24, 24), 256, 0, stream>>>(wvip, wkvipT, 768, 768, 768, 768);

  // --- projections ---
  q_proj_gemm<<<dim3(12, 64), 256, 0, stream>>>(hsbf, wqT, rc, rsn, qbuf);
  kv_gemm<<<dim3(12, 16), 256, 0, stream>>>(textbf, wkvT, kbuf, vtbuf, 9);
  kv_gemm<<<dim3(12, 2), 256, 0, stream>>>(ipbf, wkvipT, kipbuf, vtipbuf, 6);

  // --- attention ---
  attn_kernel<<<3072, 256, 0, stream>>>(qbuf, kbuf, vtbuf, kipbuf,
                                        vtipbuf, attnbuf);

  // --- output projection + bias + residual ---
  o_proj_gemm<<<dim3(12, 64), 256, 0, stream>>>(attnbuf, woT, bo, hs, out);
}

// Round 5
// 260.049 us; speedup vs baseline: 3.1546x; 1.0478x over previous
//
#include <hip/hip_runtime.h>
#include <hip/hip_bf16.h>

typedef __attribute__((ext_vector_type(8))) short short8;
typedef __attribute__((ext_vector_type(4))) short short4v;
typedef __attribute__((ext_vector_type(4))) float f32x4;

#define MFMA16(a, b, c) __builtin_amdgcn_mfma_f32_16x16x32_bf16(a, b, c, 0, 0, 0)
#define QK_SCALE_LOG2E 0.18033688011112042f  // (1/8) * log2(e)

__device__ __forceinline__ short f2bf(float x) {
  union { float f; unsigned u; } v; v.f = x;
  unsigned u = v.u;
  u += 0x7FFFu + ((u >> 16) & 1u);  // RNE
  return (short)(u >> 16);
}

__device__ __forceinline__ void gload16(const void* g, void* l) {
  __builtin_amdgcn_global_load_lds(
      (const __attribute__((address_space(1))) unsigned int*)g,
      (__attribute__((address_space(3))) unsigned int*)l, 16, 0, 0);
}

// ---------------------------------------------------------------------------
// Pre-pass kernels: f32 -> bf16 convert / pack / transpose
// ---------------------------------------------------------------------------
__global__ __launch_bounds__(256) void conv_bf16_kernel(
    const float* __restrict__ in, short* __restrict__ out, int n4) {
  int i = blockIdx.x * 256 + threadIdx.x;
  if (i >= n4) return;
  f32x4 v = *(const f32x4*)(in + (size_t)i * 4);
  short4v s;
  s[0] = f2bf(v[0]); s[1] = f2bf(v[1]); s[2] = f2bf(v[2]); s[3] = f2bf(v[3]);
  *(short4v*)(out + (size_t)i * 4) = s;
}

// enc (4 x 576 x 768 f32) -> text_bf (4*512 x 768) + ip_bf (4*64 x 768)
__global__ __launch_bounds__(256) void enc_pack_kernel(
    const float* __restrict__ enc, short* __restrict__ text,
    short* __restrict__ ip) {
  int i4 = blockIdx.x * 256 + threadIdx.x;
  int i = i4 * 4;
  if (i >= 4 * 576 * 768) return;
  int c = i % 768;
  int rs = i / 768;
  int b = rs / 576, s = rs % 576;
  f32x4 v = *(const f32x4*)(enc + i);
  short4v o;
  o[0] = f2bf(v[0]); o[1] = f2bf(v[1]); o[2] = f2bf(v[2]); o[3] = f2bf(v[3]);
  if (s < 512)
    *(short4v*)(text + (size_t)(b * 512 + s) * 768 + c) = o;
  else
    *(short4v*)(ip + (size_t)(b * 64 + (s - 512)) * 768 + c) = o;
}

// All weight transposes fused: z selects which square weight to transpose.
__global__ __launch_bounds__(256) void prep_weights_kernel(
    const float* __restrict__ wq, const float* __restrict__ wo,
    const float* __restrict__ wk, const float* __restrict__ wv,
    const float* __restrict__ wkip, const float* __restrict__ wvip,
    short* __restrict__ wqT, short* __restrict__ woT,
    short* __restrict__ wkvT, short* __restrict__ wkvipT) {
  __shared__ float tile[32][33];
  const int z = blockIdx.z;
  const float* src; short* dst; int N, row_off;
  if (z == 0)      { src = wq;   dst = wqT;    N = 1536; row_off = 0; }
  else if (z == 1) { src = wo;   dst = woT;    N = 1536; row_off = 0; }
  else if (z == 2) { src = wk;   dst = wkvT;   N = 768;  row_off = 0; }
  else if (z == 3) { src = wv;   dst = wkvT;   N = 768;  row_off = 768; }
  else if (z == 4) { src = wkip; dst = wkvipT; N = 768;  row_off = 0; }
  else             { src = wvip; dst = wkvipT; N = 768;  row_off = 768; }
  int c0 = blockIdx.x * 32, r0 = blockIdx.y * 32;
  if (c0 >= N || r0 >= N) return;
  int tx = threadIdx.x & 31, ty = threadIdx.x >> 5;  // ty 0..7
#pragma unroll
  for (int j = 0; j < 4; ++j)
    tile[ty + j * 8][tx] = src[(size_t)(r0 + ty + j * 8) * N + c0 + tx];
  __syncthreads();
#pragma unroll
  for (int j = 0; j < 4; ++j)
    dst[(size_t)(row_off + c0 + ty + j * 8) * N + r0 + tx] =
        f2bf(tile[tx][ty + j * 8]);
}

// ---------------------------------------------------------------------------
// 128x128-tile GEMM core (kept for the small K/V projections).
// ---------------------------------------------------------------------------
__device__ __forceinline__ void gemm_core(
    const short* __restrict__ A, const short* __restrict__ Bt, int K, int lda,
    int ldb, int row0, int col0, short* sA, short* sB, f32x4 acc[4][4]) {
  const int tid = threadIdx.x;
  const int lane = tid & 63;
  const int wid = tid >> 6;
  const int wr = (wid >> 1) * 64, wc = (wid & 1) * 64;
  const int lr = lane & 15;
  const int hk = (lane >> 4) * 16;
  const int xr = (lr & 7) << 4;

  for (int kt = 0; kt < K; kt += 64) {
#pragma unroll
    for (int q = 0; q < 4; ++q) {
      int L = q * 4096 + tid * 16;
      int r = L >> 7;
      int sb = (L & 127) ^ ((r & 7) << 4);
      int srcoff = kt + (sb >> 1);
      gload16(A + (size_t)(row0 + r) * lda + srcoff, (char*)sA + L);
      gload16(Bt + (size_t)(col0 + r) * ldb + srcoff, (char*)sB + L);
    }
    __syncthreads();
#pragma unroll
    for (int kk = 0; kk < 2; ++kk) {
      short8 af[4], bf[4];
#pragma unroll
      for (int m = 0; m < 4; ++m) {
        int row = wr + m * 16 + lr;
        af[m] = *(const short8*)((const char*)sA + row * 128 +
                                 ((kk * 64 + hk) ^ xr));
      }
#pragma unroll
      for (int n = 0; n < 4; ++n) {
        int row = wc + n * 16 + lr;
        bf[n] = *(const short8*)((const char*)sB + row * 128 +
                                 ((kk * 64 + hk) ^ xr));
      }
#pragma unroll
      for (int m = 0; m < 4; ++m)
#pragma unroll
        for (int n = 0; n < 4; ++n) acc[m][n] = MFMA16(af[m], bf[n], acc[m][n]);
    }
    __syncthreads();
  }
}

// ---------------------------------------------------------------------------
// 256x128-tile, 8-wave, 3-buffer phase-split pipelined GEMM core.
// Waves 4M x 2N, per-wave 64x64. BK=64. Per K-tile: 2 phases x 16 MFMA.
// LDS: 3 buffers x (A 32KB + B 16KB) = 144 KB (dynamic).
// Pipeline ledger (per-wave loads: A=4, B=2 per tile -> 6/tile):
//   prologue: stage t0 -> p0 (6), t1 -> p1 (6); vmcnt(6) [t0 landed]; barrier
//   tile T: phA stages A(T+2)->p2, phB stages B(T+2)->p2;
//     end of T: vmcnt(6) leaves exactly T+2's 6 in flight => T+1's stages
//     (issued during T-1) have landed; barrier publishes cross-wave.
//   WAR: p2 == buffer last read at tile T-1, whose reads completed before
//     T-1's end barrier (sched_barrier(0) pins MFMA+lgkm waits above it).
//   Tail (T >= NT-2): no stages issued; drain with vmcnt(0).
// ---------------------------------------------------------------------------
__device__ __forceinline__ void stageA256(const short* __restrict__ A, int lda,
                                          int row0, int kt, char* dst, int tid) {
#pragma unroll
  for (int l = 0; l < 4; ++l) {
    int L = l * 8192 + tid * 16;
    int r = L >> 7;
    int cb = (L & 127) ^ ((r & 7) << 4);
    gload16(A + (size_t)(row0 + r) * lda + kt + (cb >> 1), dst + L);
  }
}
__device__ __forceinline__ void stageB256(const short* __restrict__ Bt, int ldb,
                                          int col0, int kt, char* dst, int tid) {
#pragma unroll
  for (int l = 0; l < 2; ++l) {
    int L = l * 8192 + tid * 16;
    int r = L >> 7;
    int cb = (L & 127) ^ ((r & 7) << 4);
    gload16(Bt + (size_t)(col0 + r) * ldb + kt + (cb >> 1), dst + L);
  }
}

template <int K>
__device__ __forceinline__ void gemm256core(
    const short* __restrict__ A, const short* __restrict__ Bt, int lda, int ldb,
    int row0, int col0, char* smem, f32x4 acc[4][4]) {
  const int tid = threadIdx.x;
  const int lane = tid & 63, wid = tid >> 6;
  const int wr = wid >> 1, wc = wid & 1;
  const int lr = lane & 15, hk = (lane >> 4) * 16;
  const int xr = (lr & 7) << 4;
  constexpr int NT = K / 64;

  char* p0 = smem;
  char* p1 = smem + 49152;
  char* p2 = smem + 2 * 49152;

  stageA256(A, lda, row0, 0, p0, tid);
  stageB256(Bt, ldb, col0, 0, p0 + 32768, tid);
  stageA256(A, lda, row0, 64, p1, tid);
  stageB256(Bt, ldb, col0, 64, p1 + 32768, tid);
  asm volatile("s_waitcnt vmcnt(6)" ::: "memory");
  __builtin_amdgcn_s_barrier();

  for (int T = 0; T < NT; ++T) {
    const int kt2 = (T + 2) * 64;
    const bool pre = (T + 2 < NT);
    // ---- phase A: stage A(T+2), read af[0..1] + all bf, 16 MFMA ----
    if (pre) stageA256(A, lda, row0, kt2, p2, tid);
    short8 af0[2][2], bf[4][2];
#pragma unroll
    for (int m = 0; m < 2; ++m)
#pragma unroll
      for (int kk = 0; kk < 2; ++kk) {
        int row = wr * 64 + m * 16 + lr;
        af0[m][kk] = *(const short8*)(p0 + row * 128 + ((kk * 64 + hk) ^ xr));
      }
#pragma unroll
    for (int n = 0; n < 4; ++n)
#pragma unroll
      for (int kk = 0; kk < 2; ++kk) {
        int row = wc * 64 + n * 16 + lr;
        bf[n][kk] =
            *(const short8*)(p0 + 32768 + row * 128 + ((kk * 64 + hk) ^ xr));
      }
    __builtin_amdgcn_s_barrier();
    __builtin_amdgcn_s_setprio(1);
#pragma unroll
    for (int m = 0; m < 2; ++m)
#pragma unroll
      for (int n = 0; n < 4; ++n)
#pragma unroll
        for (int kk = 0; kk < 2; ++kk)
          acc[m][n] = MFMA16(af0[m][kk], bf[n][kk], acc[m][n]);
    __builtin_amdgcn_s_setprio(0);
    __builtin_amdgcn_s_barrier();
    // ---- phase B: stage B(T+2), read af[2..3], 16 MFMA ----
    if (pre) stageB256(Bt, ldb, col0, kt2, p2 + 32768, tid);
    short8 af1[2][2];
#pragma unroll
    for (int m = 0; m < 2; ++m)
#pragma unroll
      for (int kk = 0; kk < 2; ++kk) {
        int row = wr * 64 + (m + 2) * 16 + lr;
        af1[m][kk] = *(const short8*)(p0 + row * 128 + ((kk * 64 + hk) ^ xr));
      }
    __builtin_amdgcn_s_barrier();
    __builtin_amdgcn_s_setprio(1);
#pragma unroll
    for (int m = 0; m < 2; ++m)
#pragma unroll
      for (int n = 0; n < 4; ++n)
#pragma unroll
        for (int kk = 0; kk < 2; ++kk)
          acc[m + 2][n] = MFMA16(af1[m][kk], bf[n][kk], acc[m + 2][n]);
    __builtin_amdgcn_s_setprio(0);
    // boundary: pin MFMAs + their lgkm waits above; counted drain; publish
    __builtin_amdgcn_sched_barrier(0);
    if (T < NT - 2)
      asm volatile("s_waitcnt vmcnt(6)" ::: "memory");
    else
      asm volatile("s_waitcnt vmcnt(0)" ::: "memory");
    __builtin_amdgcn_s_barrier();
    char* t = p0; p0 = p1; p1 = p2; p2 = t;
  }
}

// grid: 384 blocks (12 col-tiles x 32 row-tiles), XCD-swizzled.
__device__ __forceinline__ void grid256(int& row0, int& col0) {
  int bid = blockIdx.x;
  int swz = (bid & 7) * 48 + (bid >> 3);  // 384 % 8 == 0: bijective
  col0 = (swz / 32) * 128;
  row0 = (swz % 32) * 256;
}

// ---------------------------------------------------------------------------
// Q projection (256x128 pipelined) + RoPE + pre-scale -> qbuf bf16 (B,H,S,64)
// ---------------------------------------------------------------------------
__global__ __launch_bounds__(512, 2) void q_proj_256(
    const short* __restrict__ hsbf, const short* __restrict__ wqT,
    const float* __restrict__ rc, const float* __restrict__ rsn,
    short* __restrict__ qbuf) {
  extern __shared__ char smem[];
  int row0, col0;
  grid256(row0, col0);
  f32x4 acc[4][4] = {};
  gemm256core<1536>(hsbf, wqT, 1536, 1536, row0, col0, smem, acc);

  const int lane = threadIdx.x & 63, wid = threadIdx.x >> 6;
  const int wr = wid >> 1, wc = wid & 1;
  const int lr = lane & 15, hi4 = (lane >> 4) * 4;
  const int h = (col0 + wc * 64) >> 6;
#pragma unroll
  for (int m = 0; m < 4; ++m) {
#pragma unroll
    for (int r = 0; r < 4; ++r) {
      int grow = row0 + wr * 64 + m * 16 + hi4 + r;
      int b = grow >> 11, t = grow & 2047;
      float v0 = acc[m][0][r], v1 = acc[m][1][r];
      float c0 = rc[t * 32 + lr], s0 = rsn[t * 32 + lr];
      float c1 = rc[t * 32 + 16 + lr], s1 = rsn[t * 32 + 16 + lr];
      float n0 = (v0 * c0 - v1 * s0) * QK_SCALE_LOG2E;
      float n1 = (v1 * c1 + v0 * s1) * QK_SCALE_LOG2E;
      short* ob = qbuf + ((size_t)(b * 24 + h) * 2048 + t) * 64;
      ob[lr] = f2bf(n0);
      ob[16 + lr] = f2bf(n1);
      ob[32 + lr] = f2bf(acc[m][2][r] * QK_SCALE_LOG2E);
      ob[48 + lr] = f2bf(acc[m][3][r] * QK_SCALE_LOG2E);
    }
  }
}

// ---------------------------------------------------------------------------
// Output projection (256x128 pipelined) + bias + residual -> f32
// ---------------------------------------------------------------------------
__global__ __launch_bounds__(512, 2) void o_proj_256(
    const short* __restrict__ attnbf, const short* __restrict__ woT,
    const float* __restrict__ bo, const float* __restrict__ resid,
    float* __restrict__ out) {
  extern __shared__ char smem[];
  int row0, col0;
  grid256(row0, col0);
  f32x4 acc[4][4] = {};
  gemm256core<1536>(attnbf, woT, 1536, 1536, row0, col0, smem, acc);

  const int lane = threadIdx.x & 63, wid = threadIdx.x >> 6;
  const int wr = wid >> 1, wc = wid & 1;
  const int lr = lane & 15, hi4 = (lane >> 4) * 4;
#pragma unroll
  for (int m = 0; m < 4; ++m) {
#pragma unroll
    for (int n = 0; n < 4; ++n) {
#pragma unroll
      for (int r = 0; r < 4; ++r) {
        int grow = row0 + wr * 64 + m * 16 + hi4 + r;
        int gcol = col0 + wc * 64 + n * 16 + lr;
        size_t off = (size_t)grow * 1536 + gcol;
        out[off] = acc[m][n][r] + bo[gcol] + resid[off];
      }
    }
  }
}

// ---------------------------------------------------------------------------
// Fused K|V projection GEMM (128x128 core; small shapes).
// ---------------------------------------------------------------------------
__global__ __launch_bounds__(256) void kv_gemm(
    const short* __restrict__ Abf, const short* __restrict__ wkvT,
    short* __restrict__ kout, short* __restrict__ vtout, int rlog2) {
  __shared__ short sA[128 * 64];
  __shared__ short sB[128 * 64];
  f32x4 acc[4][4] = {};
  const int row0 = blockIdx.y * 128, col0 = blockIdx.x * 128;
  gemm_core(Abf, wkvT, 768, 768, 768, row0, col0, sA, sB, acc);

  const int tid = threadIdx.x;
  const int lane = tid & 63, wid = tid >> 6;
  const int wr = (wid >> 1) * 64, wc = (wid & 1) * 64;
  const int lr = lane & 15, lrow4 = (lane >> 4) * 4;
  const int rmask = (1 << rlog2) - 1;
#pragma unroll
  for (int m = 0; m < 4; ++m) {
#pragma unroll
    for (int n = 0; n < 4; ++n) {
#pragma unroll
      for (int r = 0; r < 4; ++r) {
        int grow = row0 + wr + m * 16 + lrow4 + r;
        int gcol = col0 + wc + n * 16 + lr;
        int b = grow >> rlog2, key = grow & rmask;
        short val = f2bf(acc[m][n][r]);
        if (gcol < 768) {
          int kvh = gcol >> 6, d = gcol & 63;
          kout[((((size_t)(b * 12 + kvh)) << rlog2) + key) * 64 + d] = val;
        } else {
          int c2 = gcol - 768;
          int kvh = c2 >> 6, d = c2 & 63;
          vtout[(((size_t)((b * 12 + kvh) * 64 + d)) << rlog2) + key] = val;
        }
      }
    }
  }
}

// ---------------------------------------------------------------------------
// Attention (unchanged from round 4).
// ---------------------------------------------------------------------------
__device__ __forceinline__ void stage_tile(const short* __restrict__ ks,
                                           const short* __restrict__ vs,
                                           int vstr, short* kb, short* vb,
                                           int tid) {
#pragma unroll
  for (int q = 0; q < 2; ++q) {
    int L = q * 4096 + tid * 16;
    int row = L >> 7;
    int sc = ((L & 127) ^ ((row & 7) << 4)) >> 1;
    gload16(ks + row * 64 + sc, (char*)kb + L);
    gload16(vs + (size_t)row * vstr + sc, (char*)vb + L);
  }
}

__device__ __forceinline__ void attn_tile(const short* kb, const short* vb,
                                          short (*sP)[72], const short8 qf[2],
                                          float& m_run, float& l_run,
                                          f32x4 o_acc[4], int lane) {
  const int lr = lane & 15, hi = lane >> 4;
  f32x4 s[4];
#pragma unroll
  for (int nf = 0; nf < 4; ++nf) {
    int row = nf * 16 + lr;
    int rx = (row & 7) << 4;
    const char* base = (const char*)kb + row * 128;
    short8 k0 = *(const short8*)(base + ((hi * 16) ^ rx));
    short8 k1 = *(const short8*)(base + ((64 + hi * 16) ^ rx));
    f32x4 a = {0.f, 0.f, 0.f, 0.f};
    a = MFMA16(k0, qf[0], a);
    a = MFMA16(k1, qf[1], a);
    s[nf] = a;
  }
  float mx = s[0][0];
#pragma unroll
  for (int nf = 0; nf < 4; ++nf)
#pragma unroll
    for (int r = 0; r < 4; ++r) mx = fmaxf(mx, s[nf][r]);
  mx = fmaxf(mx, __shfl_xor(mx, 16));
  mx = fmaxf(mx, __shfl_xor(mx, 32));
  if (__any(mx - m_run > 8.0f)) {
    float mn = fmaxf(m_run, mx);
    float corr = __builtin_amdgcn_exp2f(m_run - mn);
    m_run = mn;
    l_run *= corr;
#pragma unroll
    for (int r = 0; r < 4; ++r) {
      float cr = __shfl(corr, hi * 4 + r);
#pragma unroll
      for (int no = 0; no < 4; ++no) o_acc[no][r] *= cr;
    }
  }
  float rs = 0.f;
#pragma unroll
  for (int nf = 0; nf < 4; ++nf) {
    short4v pk;
#pragma unroll
    for (int r = 0; r < 4; ++r) {
      float p = __builtin_amdgcn_exp2f(s[nf][r] - m_run);
      rs += p;
      pk[r] = f2bf(p);
    }
    *(short4v*)&sP[lr][nf * 16 + hi * 4] = pk;
  }
  rs += __shfl_xor(rs, 16);
  rs += __shfl_xor(rs, 32);
  l_run += rs;
#pragma unroll
  for (int ks = 0; ks < 2; ++ks) {
    short8 pa = *(const short8*)&sP[lr][ks * 32 + hi * 8];
#pragma unroll
    for (int no = 0; no < 4; ++no) {
      int row = no * 16 + lr;
      int rx = (row & 7) << 4;
      short8 vf = *(const short8*)((const char*)vb + row * 128 +
                                   ((ks * 64 + hi * 16) ^ rx));
      o_acc[no] = MFMA16(pa, vf, o_acc[no]);
    }
  }
}

__global__ __launch_bounds__(256, 3) void attn_kernel(
    const short* __restrict__ qbuf, const short* __restrict__ kbuf,
    const short* __restrict__ vtbuf, const short* __restrict__ kipbuf,
    const short* __restrict__ vtipbuf, short* __restrict__ attn_out) {
  const int tid = threadIdx.x;
  const int lane = tid & 63, wid = tid >> 6;
  const int f = (blockIdx.x & 7) * 384 + (blockIdx.x >> 3);
  const int qt = f & 31;
  const int h = (f >> 5) % 24;
  const int b = f / (32 * 24);
  const int kvh = h >> 1;
  const int lr = lane & 15, hi = lane >> 4;

  __shared__ short skv_k[2 * 64 * 64];
  __shared__ short skv_v[2 * 64 * 64];
  __shared__ short sPall[4][16][72];
  short(*sP)[72] = sPall[wid];

  const short* qp = qbuf + (size_t)(b * 24 + h) * 2048 * 64;
  const short* kp = kbuf + (size_t)(b * 12 + kvh) * 512 * 64;
  const short* vp = vtbuf + (size_t)(b * 12 + kvh) * 64 * 512;
  const short* kip = kipbuf + (size_t)(b * 12 + kvh) * 64 * 64;
  const short* vip = vtipbuf + (size_t)(b * 12 + kvh) * 64 * 64;

  const int q0 = qt * 64 + wid * 16;
  short8 qf[2];
  qf[0] = *(const short8*)(qp + (size_t)(q0 + lr) * 64 + hi * 8);
  qf[1] = *(const short8*)(qp + (size_t)(q0 + lr) * 64 + 32 + hi * 8);

  float m1 = -1.0e30f, l1 = 0.f, m2 = -1.0e30f, l2 = 0.f;
  f32x4 oacc1[4] = {}, oacc2[4] = {};

  stage_tile(kp, vp, 512, skv_k, skv_v, tid);
  __syncthreads();

  for (int t = 0; t < 9; ++t) {
    int cur = t & 1, nxt = cur ^ 1;
    if (t < 8) {
      const short* ks_ = (t < 7) ? kp + (t + 1) * 64 * 64 : kip;
      const short* vs_ = (t < 7) ? vp + (t + 1) * 64 : vip;
      int vstr = (t < 7) ? 512 : 64;
      stage_tile(ks_, vs_, vstr, skv_k + nxt * 4096, skv_v + nxt * 4096, tid);
    }
    if (t < 8)
      attn_tile(skv_k + cur * 4096, skv_v + cur * 4096, sP, qf, m1, l1, oacc1, lane);
    else
      attn_tile(skv_k + cur * 4096, skv_v + cur * 4096, sP, qf, m2, l2, oacc2, lane);
    __syncthreads();
  }

  float inv1 = 1.0f / l1, inv2 = 1.0f / l2;
#pragma unroll
  for (int r = 0; r < 4; ++r) {
    float i1 = __shfl(inv1, hi * 4 + r);
    float i2 = __shfl(inv2, hi * 4 + r);
    int grow = b * 2048 + q0 + hi * 4 + r;
#pragma unroll
    for (int no = 0; no < 4; ++no) {
      float val = oacc1[no][r] * i1 + oacc2[no][r] * i2;
      attn_out[(size_t)grow * 1536 + h * 64 + no * 16 + lr] = f2bf(val);
    }
  }
}

// ---------------------------------------------------------------------------
extern "C" void kernel_launch(void* const* d_in, const int* in_sizes, int n_in,
                              void* d_out, int out_size, void* d_ws, size_t ws_size,
                              hipStream_t stream) {
  const float* hs = (const float*)d_in[0];
  const float* enc = (const float*)d_in[1];
  const float* rc = (const float*)d_in[2];
  const float* rsn = (const float*)d_in[3];
  const float* wq = (const float*)d_in[4];
  const float* wk = (const float*)d_in[5];
  const float* wv = (const float*)d_in[6];
  const float* wkip = (const float*)d_in[7];
  const float* wvip = (const float*)d_in[8];
  const float* wo = (const float*)d_in[9];
  const float* bo = (const float*)d_in[10];
  float* out = (float*)d_out;

  char* ws = (char*)d_ws;
  short* hsbf    = (short*)(ws + 0);          // 25165824 B (aliased by attnbuf)
  short* attnbuf = (short*)(ws + 0);          // reuse: hsbf dead after q_proj
  short* qbuf    = (short*)(ws + 25165824);   // 25165824
  short* kbuf    = (short*)(ws + 50331648);   //  3145728
  short* vtbuf   = (short*)(ws + 53477376);   //  3145728
  short* kipbuf  = (short*)(ws + 56623104);   //   393216
  short* vtipbuf = (short*)(ws + 57016320);   //   393216
  short* textbf  = (short*)(ws + 57409536);   //  3145728
  short* ipbf    = (short*)(ws + 60555264);   //   393216
  short* wqT     = (short*)(ws + 60948480);   //  4718592
  short* woT     = (short*)(ws + 65667072);   //  4718592
  short* wkvT    = (short*)(ws + 70385664);   //  2359296
  short* wkvipT  = (short*)(ws + 72744960);   //  2359296
  // total 75104256 bytes

  static bool attr_done = false;
  (void)attr_done;
  hipFuncSetAttribute((const void*)q_proj_256,
                      hipFuncAttributeMaxDynamicSharedMemorySize, 147456);
  hipFuncSetAttribute((const void*)o_proj_256,
                      hipFuncAttributeMaxDynamicSharedMemorySize, 147456);

  // --- pre-pass: convert/pack/transpose to bf16 ---
  conv_bf16_kernel<<<12288, 256, 0, stream>>>(hs, hsbf, 8192 * 1536 / 4);
  enc_pack_kernel<<<1728, 256, 0, stream>>>(enc, textbf, ipbf);
  prep_weights_kernel<<<dim3(48, 48, 6), 256, 0, stream>>>(
      wq, wo, wk, wv, wkip, wvip, wqT, woT, wkvT, wkvipT);

  // --- projections ---
  q_proj_256<<<384, 512, 147456, stream>>>(hsbf, wqT, rc, rsn, qbuf);
  kv_gemm<<<dim3(12, 16), 256, 0, stream>>>(textbf, wkvT, kbuf, vtbuf, 9);
  kv_gemm<<<dim3(12, 2), 256, 0, stream>>>(ipbf, wkvipT, kipbuf, vtipbuf, 6);

  // --- attention ---
  attn_kernel<<<3072, 256, 0, stream>>>(qbuf, kbuf, vtbuf, kipbuf,
                                        vtipbuf, attnbuf);

  // --- output projection + bias + residual ---
  o_proj_256<<<384, 512, 147456, stream>>>(attnbuf, woT, bo, hs, out);
}

// Round 6
// 224.685 us; speedup vs baseline: 3.6511x; 1.1574x over previous
//
#include <hip/hip_runtime.h>
#include <hip/hip_bf16.h>

typedef __attribute__((ext_vector_type(8))) short short8;
typedef __attribute__((ext_vector_type(4))) short short4v;
typedef __attribute__((ext_vector_type(4))) float f32x4;

#define MFMA16(a, b, c) __builtin_amdgcn_mfma_f32_16x16x32_bf16(a, b, c, 0, 0, 0)
#define QK_SCALE_LOG2E 0.18033688011112042f  // (1/8) * log2(e)

__device__ __forceinline__ short f2bf(float x) {
  union { float f; unsigned u; } v; v.f = x;
  unsigned u = v.u;
  u += 0x7FFFu + ((u >> 16) & 1u);  // RNE
  return (short)(u >> 16);
}
__device__ __forceinline__ short f2bf_trunc(float x) {
  union { float f; unsigned u; } v; v.f = x;
  return (short)(v.u >> 16);
}

__device__ __forceinline__ void gload16(const void* g, void* l) {
  __builtin_amdgcn_global_load_lds(
      (const __attribute__((address_space(1))) unsigned int*)g,
      (__attribute__((address_space(3))) unsigned int*)l, 16, 0, 0);
}

// ---------------------------------------------------------------------------
// Pre-pass kernels: f32 -> bf16 convert / pack / transpose
// ---------------------------------------------------------------------------
__global__ __launch_bounds__(256) void conv_bf16_kernel(
    const float* __restrict__ in, short* __restrict__ out, int n4) {
  int i = blockIdx.x * 256 + threadIdx.x;
  if (i >= n4) return;
  f32x4 v = *(const f32x4*)(in + (size_t)i * 4);
  short4v s;
  s[0] = f2bf(v[0]); s[1] = f2bf(v[1]); s[2] = f2bf(v[2]); s[3] = f2bf(v[3]);
  *(short4v*)(out + (size_t)i * 4) = s;
}

// enc (4 x 576 x 768 f32) -> text_bf (4*512 x 768) + ip_bf (4*64 x 768)
__global__ __launch_bounds__(256) void enc_pack_kernel(
    const float* __restrict__ enc, short* __restrict__ text,
    short* __restrict__ ip) {
  int i4 = blockIdx.x * 256 + threadIdx.x;
  int i = i4 * 4;
  if (i >= 4 * 576 * 768) return;
  int c = i % 768;
  int rs = i / 768;
  int b = rs / 576, s = rs % 576;
  f32x4 v = *(const f32x4*)(enc + i);
  short4v o;
  o[0] = f2bf(v[0]); o[1] = f2bf(v[1]); o[2] = f2bf(v[2]); o[3] = f2bf(v[3]);
  if (s < 512)
    *(short4v*)(text + (size_t)(b * 512 + s) * 768 + c) = o;
  else
    *(short4v*)(ip + (size_t)(b * 64 + (s - 512)) * 768 + c) = o;
}

// All weight transposes fused: z selects which square weight to transpose.
__global__ __launch_bounds__(256) void prep_weights_kernel(
    const float* __restrict__ wq, const float* __restrict__ wo,
    const float* __restrict__ wk, const float* __restrict__ wv,
    const float* __restrict__ wkip, const float* __restrict__ wvip,
    short* __restrict__ wqT, short* __restrict__ woT,
    short* __restrict__ wkvT, short* __restrict__ wkvipT) {
  __shared__ float tile[32][33];
  const int z = blockIdx.z;
  const float* src; short* dst; int N, row_off;
  if (z == 0)      { src = wq;   dst = wqT;    N = 1536; row_off = 0; }
  else if (z == 1) { src = wo;   dst = woT;    N = 1536; row_off = 0; }
  else if (z == 2) { src = wk;   dst = wkvT;   N = 768;  row_off = 0; }
  else if (z == 3) { src = wv;   dst = wkvT;   N = 768;  row_off = 768; }
  else if (z == 4) { src = wkip; dst = wkvipT; N = 768;  row_off = 0; }
  else             { src = wvip; dst = wkvipT; N = 768;  row_off = 768; }
  int c0 = blockIdx.x * 32, r0 = blockIdx.y * 32;
  if (c0 >= N || r0 >= N) return;
  int tx = threadIdx.x & 31, ty = threadIdx.x >> 5;  // ty 0..7
#pragma unroll
  for (int j = 0; j < 4; ++j)
    tile[ty + j * 8][tx] = src[(size_t)(r0 + ty + j * 8) * N + c0 + tx];
  __syncthreads();
#pragma unroll
  for (int j = 0; j < 4; ++j)
    dst[(size_t)(row_off + c0 + ty + j * 8) * N + r0 + tx] =
        f2bf(tile[tx][ty + j * 8]);
}

// ---------------------------------------------------------------------------
// 128x128-tile GEMM core, single-buffered (kept for small K/V projections).
// ---------------------------------------------------------------------------
__device__ __forceinline__ void gemm_core(
    const short* __restrict__ A, const short* __restrict__ Bt, int K, int lda,
    int ldb, int row0, int col0, short* sA, short* sB, f32x4 acc[4][4]) {
  const int tid = threadIdx.x;
  const int lane = tid & 63;
  const int wid = tid >> 6;
  const int wr = (wid >> 1) * 64, wc = (wid & 1) * 64;
  const int lr = lane & 15;
  const int hk = (lane >> 4) * 16;
  const int xr = (lr & 7) << 4;

  for (int kt = 0; kt < K; kt += 64) {
#pragma unroll
    for (int q = 0; q < 4; ++q) {
      int L = q * 4096 + tid * 16;
      int r = L >> 7;
      int sb = (L & 127) ^ ((r & 7) << 4);
      int srcoff = kt + (sb >> 1);
      gload16(A + (size_t)(row0 + r) * lda + srcoff, (char*)sA + L);
      gload16(Bt + (size_t)(col0 + r) * ldb + srcoff, (char*)sB + L);
    }
    __syncthreads();
#pragma unroll
    for (int kk = 0; kk < 2; ++kk) {
      short8 af[4], bf[4];
#pragma unroll
      for (int m = 0; m < 4; ++m) {
        int row = wr + m * 16 + lr;
        af[m] = *(const short8*)((const char*)sA + row * 128 +
                                 ((kk * 64 + hk) ^ xr));
      }
#pragma unroll
      for (int n = 0; n < 4; ++n) {
        int row = wc + n * 16 + lr;
        bf[n] = *(const short8*)((const char*)sB + row * 128 +
                                 ((kk * 64 + hk) ^ xr));
      }
#pragma unroll
      for (int m = 0; m < 4; ++m)
#pragma unroll
        for (int n = 0; n < 4; ++n) acc[m][n] = MFMA16(af[m], bf[n], acc[m][n]);
    }
    __syncthreads();
  }
}

// ---------------------------------------------------------------------------
// 128x128-tile, BK=32, FULL double-buffer GEMM core. 4 waves, 3 blocks/CU
// (32 KB LDS). One __syncthreads per K-tile: it both drains vmcnt (tile T+1
// staged into the other buffer this iteration) and publishes the swap.
// Race ledger: stage(T+1) targets buf[(T+1)&1], read this tile = buf[T&1]
// (disjoint); after the barrier all reads of buf[T&1] are complete, so the
// next iteration's stage(T+2) into buf[T&1] is WAR-safe.
// 64B LDS rows, XOR swizzle byte^=((row&3)<<4) applied on BOTH sides.
// ---------------------------------------------------------------------------
__device__ __forceinline__ void stage32(const short* __restrict__ gA,
                                        const short* __restrict__ gBt,
                                        int lda, int ldb, char* buf, int tid) {
#pragma unroll
  for (int li = 0; li < 2; ++li) {
    int L = li * 4096 + tid * 16;
    int row = L >> 6;                      // 0..127
    int cb = (L & 63) ^ ((row & 3) << 4);  // inverse-swizzled source col byte
    gload16(gA + (size_t)row * lda + (cb >> 1), buf + L);
    gload16(gBt + (size_t)row * ldb + (cb >> 1), buf + 8192 + L);
  }
}

template <int K>
__device__ __forceinline__ void gemm128p(
    const short* __restrict__ A, const short* __restrict__ Bt, int lda,
    int ldb, int row0, int col0, char* sm, f32x4 acc[4][4]) {
  const int tid = threadIdx.x;
  const int lane = tid & 63, wid = tid >> 6;
  const int wr = (wid >> 1) * 64, wc = (wid & 1) * 64;
  const int lr = lane & 15;
  const int hk = (lane >> 4) * 16;   // byte col of this lane's 8-short group
  const int xr = (lr & 3) << 4;      // read-side XOR swizzle (64B rows)
  constexpr int NT = K / 32;

  const short* gA = A + (size_t)row0 * lda;
  const short* gB = Bt + (size_t)col0 * ldb;

  stage32(gA, gB, lda, ldb, sm, tid);  // tile 0 -> buf 0
  __syncthreads();

  for (int t = 0; t < NT; ++t) {
    char* cur = sm + (t & 1) * 16384;
    if (t + 1 < NT)
      stage32(gA + (t + 1) * 32, gB + (t + 1) * 32, lda, ldb,
              sm + ((t + 1) & 1) * 16384, tid);
    __builtin_amdgcn_sched_barrier(0);  // keep stage issue ahead of compute
    short8 af[4], bf[4];
#pragma unroll
    for (int m = 0; m < 4; ++m) {
      int row = wr + m * 16 + lr;
      af[m] = *(const short8*)(cur + row * 64 + (hk ^ xr));
    }
#pragma unroll
    for (int n = 0; n < 4; ++n) {
      int row = wc + n * 16 + lr;
      bf[n] = *(const short8*)(cur + 8192 + row * 64 + (hk ^ xr));
    }
#pragma unroll
    for (int m = 0; m < 4; ++m)
#pragma unroll
      for (int n = 0; n < 4; ++n) acc[m][n] = MFMA16(af[m], bf[n], acc[m][n]);
    __syncthreads();  // drains vmcnt(0)+lgkm, publishes buffer swap
  }
}

// Row-band XCD grid mapping for 768 blocks (64 row-panels x 12 col-panels).
// HW round-robins bid%8 across XCDs -> XCD x owns row-panels [x*8, x*8+8),
// sweeping cols; working set ~3MB A-band + B panels stays L2-resident.
__device__ __forceinline__ void grid128(int& row0, int& col0) {
  int bid = blockIdx.x;  // 0..767
  int x = bid & 7;
  int j = bid >> 3;      // 0..95
  row0 = (x * 8 + (j & 7)) * 128;
  col0 = (j >> 3) * 128;
}

// ---------------------------------------------------------------------------
// Q projection + RoPE + pre-scale by SCALE*log2(e) -> qbuf bf16 (B,H,S,64)
// ---------------------------------------------------------------------------
__global__ __launch_bounds__(256, 3) void q_proj_128p(
    const short* __restrict__ hsbf, const short* __restrict__ wqT,
    const float* __restrict__ rc, const float* __restrict__ rsn,
    short* __restrict__ qbuf) {
  __shared__ char sm[32768];
  f32x4 acc[4][4] = {};
  int row0, col0;
  grid128(row0, col0);
  gemm128p<1536>(hsbf, wqT, 1536, 1536, row0, col0, sm, acc);

  const int lane = threadIdx.x & 63, wid = threadIdx.x >> 6;
  const int wr = (wid >> 1) * 64, wc = (wid & 1) * 64;
  const int lr = lane & 15, lrow4 = (lane >> 4) * 4;
  const int h = (col0 + wc) >> 6;
#pragma unroll
  for (int m = 0; m < 4; ++m) {
#pragma unroll
    for (int r = 0; r < 4; ++r) {
      int grow = row0 + wr + m * 16 + lrow4 + r;
      int b = grow >> 11, t = grow & 2047;
      float v0 = acc[m][0][r], v1 = acc[m][1][r];
      float c0 = rc[t * 32 + lr], s0 = rsn[t * 32 + lr];
      float c1 = rc[t * 32 + 16 + lr], s1 = rsn[t * 32 + 16 + lr];
      float n0 = (v0 * c0 - v1 * s0) * QK_SCALE_LOG2E;
      float n1 = (v1 * c1 + v0 * s1) * QK_SCALE_LOG2E;
      short* ob = qbuf + ((size_t)(b * 24 + h) * 2048 + t) * 64;
      ob[lr] = f2bf(n0);
      ob[16 + lr] = f2bf(n1);
      ob[32 + lr] = f2bf(acc[m][2][r] * QK_SCALE_LOG2E);
      ob[48 + lr] = f2bf(acc[m][3][r] * QK_SCALE_LOG2E);
    }
  }
}

// ---------------------------------------------------------------------------
// Output projection + bias + residual -> f32
// ---------------------------------------------------------------------------
__global__ __launch_bounds__(256, 3) void o_proj_128p(
    const short* __restrict__ attnbf, const short* __restrict__ woT,
    const float* __restrict__ bo, const float* __restrict__ resid,
    float* __restrict__ out) {
  __shared__ char sm[32768];
  f32x4 acc[4][4] = {};
  int row0, col0;
  grid128(row0, col0);
  gemm128p<1536>(attnbf, woT, 1536, 1536, row0, col0, sm, acc);

  const int lane = threadIdx.x & 63, wid = threadIdx.x >> 6;
  const int wr = (wid >> 1) * 64, wc = (wid & 1) * 64;
  const int lr = lane & 15, lrow4 = (lane >> 4) * 4;
#pragma unroll
  for (int m = 0; m < 4; ++m) {
#pragma unroll
    for (int n = 0; n < 4; ++n) {
#pragma unroll
      for (int r = 0; r < 4; ++r) {
        int grow = row0 + wr + m * 16 + lrow4 + r;
        int gcol = col0 + wc + n * 16 + lr;
        size_t off = (size_t)grow * 1536 + gcol;
        out[off] = acc[m][n][r] + bo[gcol] + resid[off];
      }
    }
  }
}

// ---------------------------------------------------------------------------
// Fused K|V projection GEMM (128x128 single-buffer core; small shapes).
// ---------------------------------------------------------------------------
__global__ __launch_bounds__(256) void kv_gemm(
    const short* __restrict__ Abf, const short* __restrict__ wkvT,
    short* __restrict__ kout, short* __restrict__ vtout, int rlog2) {
  __shared__ short sA[128 * 64];
  __shared__ short sB[128 * 64];
  f32x4 acc[4][4] = {};
  const int row0 = blockIdx.y * 128, col0 = blockIdx.x * 128;
  gemm_core(Abf, wkvT, 768, 768, 768, row0, col0, sA, sB, acc);

  const int tid = threadIdx.x;
  const int lane = tid & 63, wid = tid >> 6;
  const int wr = (wid >> 1) * 64, wc = (wid & 1) * 64;
  const int lr = lane & 15, lrow4 = (lane >> 4) * 4;
  const int rmask = (1 << rlog2) - 1;
#pragma unroll
  for (int m = 0; m < 4; ++m) {
#pragma unroll
    for (int n = 0; n < 4; ++n) {
#pragma unroll
      for (int r = 0; r < 4; ++r) {
        int grow = row0 + wr + m * 16 + lrow4 + r;
        int gcol = col0 + wc + n * 16 + lr;
        int b = grow >> rlog2, key = grow & rmask;
        short val = f2bf(acc[m][n][r]);
        if (gcol < 768) {
          int kvh = gcol >> 6, d = gcol & 63;
          kout[((((size_t)(b * 12 + kvh)) << rlog2) + key) * 64 + d] = val;
        } else {
          int c2 = gcol - 768;
          int kvh = c2 >> 6, d = c2 & 63;
          vtout[(((size_t)((b * 12 + kvh) * 64 + d)) << rlog2) + key] = val;
        }
      }
    }
  }
}

// ---------------------------------------------------------------------------
// Attention: block = (b, h, 64 q rows), 4 waves x 16 q-rows.
// Swapped QK^T, LDS-staged double-buffered K/V tiles, exp2-domain softmax,
// defer-max, truncating P->bf16 conversion.
// ---------------------------------------------------------------------------
__device__ __forceinline__ void stage_tile(const short* __restrict__ ks,
                                           const short* __restrict__ vs,
                                           int vstr, short* kb, short* vb,
                                           int tid) {
#pragma unroll
  for (int q = 0; q < 2; ++q) {
    int L = q * 4096 + tid * 16;
    int row = L >> 7;
    int sc = ((L & 127) ^ ((row & 7) << 4)) >> 1;
    gload16(ks + row * 64 + sc, (char*)kb + L);
    gload16(vs + (size_t)row * vstr + sc, (char*)vb + L);
  }
}

__device__ __forceinline__ void attn_tile(const short* kb, const short* vb,
                                          short (*sP)[72], const short8 qf[2],
                                          float& m_run, float& l_run,
                                          f32x4 o_acc[4], int lane) {
  const int lr = lane & 15, hi = lane >> 4;
  f32x4 s[4];
#pragma unroll
  for (int nf = 0; nf < 4; ++nf) {
    int row = nf * 16 + lr;
    int rx = (row & 7) << 4;
    const char* base = (const char*)kb + row * 128;
    short8 k0 = *(const short8*)(base + ((hi * 16) ^ rx));
    short8 k1 = *(const short8*)(base + ((64 + hi * 16) ^ rx));
    f32x4 a = {0.f, 0.f, 0.f, 0.f};
    a = MFMA16(k0, qf[0], a);
    a = MFMA16(k1, qf[1], a);
    s[nf] = a;
  }
  float mx = s[0][0];
#pragma unroll
  for (int nf = 0; nf < 4; ++nf)
#pragma unroll
    for (int r = 0; r < 4; ++r) mx = fmaxf(mx, s[nf][r]);
  mx = fmaxf(mx, __shfl_xor(mx, 16));
  mx = fmaxf(mx, __shfl_xor(mx, 32));
  if (__any(mx - m_run > 8.0f)) {
    float mn = fmaxf(m_run, mx);
    float corr = __builtin_amdgcn_exp2f(m_run - mn);
    m_run = mn;
    l_run *= corr;
#pragma unroll
    for (int r = 0; r < 4; ++r) {
      float cr = __shfl(corr, hi * 4 + r);
#pragma unroll
      for (int no = 0; no < 4; ++no) o_acc[no][r] *= cr;
    }
  }
  float rs = 0.f;
#pragma unroll
  for (int nf = 0; nf < 4; ++nf) {
    short4v pk;
#pragma unroll
    for (int r = 0; r < 4; ++r) {
      float p = __builtin_amdgcn_exp2f(s[nf][r] - m_run);
      rs += p;
      pk[r] = f2bf_trunc(p);
    }
    *(short4v*)&sP[lr][nf * 16 + hi * 4] = pk;
  }
  rs += __shfl_xor(rs, 16);
  rs += __shfl_xor(rs, 32);
  l_run += rs;
#pragma unroll
  for (int ks = 0; ks < 2; ++ks) {
    short8 pa = *(const short8*)&sP[lr][ks * 32 + hi * 8];
#pragma unroll
    for (int no = 0; no < 4; ++no) {
      int row = no * 16 + lr;
      int rx = (row & 7) << 4;
      short8 vf = *(const short8*)((const char*)vb + row * 128 +
                                   ((ks * 64 + hi * 16) ^ rx));
      o_acc[no] = MFMA16(pa, vf, o_acc[no]);
    }
  }
}

__global__ __launch_bounds__(256, 3) void attn_kernel(
    const short* __restrict__ qbuf, const short* __restrict__ kbuf,
    const short* __restrict__ vtbuf, const short* __restrict__ kipbuf,
    const short* __restrict__ vtipbuf, short* __restrict__ attn_out) {
  const int tid = threadIdx.x;
  const int lane = tid & 63, wid = tid >> 6;
  const int f = (blockIdx.x & 7) * 384 + (blockIdx.x >> 3);
  const int qt = f & 31;
  const int h = (f >> 5) % 24;
  const int b = f / (32 * 24);
  const int kvh = h >> 1;
  const int lr = lane & 15, hi = lane >> 4;

  __shared__ short skv_k[2 * 64 * 64];
  __shared__ short skv_v[2 * 64 * 64];
  __shared__ short sPall[4][16][72];
  short(*sP)[72] = sPall[wid];

  const short* qp = qbuf + (size_t)(b * 24 + h) * 2048 * 64;
  const short* kp = kbuf + (size_t)(b * 12 + kvh) * 512 * 64;
  const short* vp = vtbuf + (size_t)(b * 12 + kvh) * 64 * 512;
  const short* kip = kipbuf + (size_t)(b * 12 + kvh) * 64 * 64;
  const short* vip = vtipbuf + (size_t)(b * 12 + kvh) * 64 * 64;

  const int q0 = qt * 64 + wid * 16;
  short8 qf[2];
  qf[0] = *(const short8*)(qp + (size_t)(q0 + lr) * 64 + hi * 8);
  qf[1] = *(const short8*)(qp + (size_t)(q0 + lr) * 64 + 32 + hi * 8);

  float m1 = -1.0e30f, l1 = 0.f, m2 = -1.0e30f, l2 = 0.f;
  f32x4 oacc1[4] = {}, oacc2[4] = {};

  stage_tile(kp, vp, 512, skv_k, skv_v, tid);
  __syncthreads();

  for (int t = 0; t < 9; ++t) {
    int cur = t & 1, nxt = cur ^ 1;
    if (t < 8) {
      const short* ks_ = (t < 7) ? kp + (t + 1) * 64 * 64 : kip;
      const short* vs_ = (t < 7) ? vp + (t + 1) * 64 : vip;
      int vstr = (t < 7) ? 512 : 64;
      stage_tile(ks_, vs_, vstr, skv_k + nxt * 4096, skv_v + nxt * 4096, tid);
    }
    if (t < 8)
      attn_tile(skv_k + cur * 4096, skv_v + cur * 4096, sP, qf, m1, l1, oacc1, lane);
    else
      attn_tile(skv_k + cur * 4096, skv_v + cur * 4096, sP, qf, m2, l2, oacc2, lane);
    __syncthreads();
  }

  float inv1 = 1.0f / l1, inv2 = 1.0f / l2;
#pragma unroll
  for (int r = 0; r < 4; ++r) {
    float i1 = __shfl(inv1, hi * 4 + r);
    float i2 = __shfl(inv2, hi * 4 + r);
    int grow = b * 2048 + q0 + hi * 4 + r;
#pragma unroll
    for (int no = 0; no < 4; ++no) {
      float val = oacc1[no][r] * i1 + oacc2[no][r] * i2;
      attn_out[(size_t)grow * 1536 + h * 64 + no * 16 + lr] = f2bf(val);
    }
  }
}

// ---------------------------------------------------------------------------
extern "C" void kernel_launch(void* const* d_in, const int* in_sizes, int n_in,
                              void* d_out, int out_size, void* d_ws, size_t ws_size,
                              hipStream_t stream) {
  const float* hs = (const float*)d_in[0];
  const float* enc = (const float*)d_in[1];
  const float* rc = (const float*)d_in[2];
  const float* rsn = (const float*)d_in[3];
  const float* wq = (const float*)d_in[4];
  const float* wk = (const float*)d_in[5];
  const float* wv = (const float*)d_in[6];
  const float* wkip = (const float*)d_in[7];
  const float* wvip = (const float*)d_in[8];
  const float* wo = (const float*)d_in[9];
  const float* bo = (const float*)d_in[10];
  float* out = (float*)d_out;

  char* ws = (char*)d_ws;
  short* hsbf    = (short*)(ws + 0);          // 25165824 B (aliased by attnbuf)
  short* attnbuf = (short*)(ws + 0);          // reuse: hsbf dead after q_proj
  short* qbuf    = (short*)(ws + 25165824);   // 25165824
  short* kbuf    = (short*)(ws + 50331648);   //  3145728
  short* vtbuf   = (short*)(ws + 53477376);   //  3145728
  short* kipbuf  = (short*)(ws + 56623104);   //   393216
  short* vtipbuf = (short*)(ws + 57016320);   //   393216
  short* textbf  = (short*)(ws + 57409536);   //  3145728
  short* ipbf    = (short*)(ws + 60555264);   //   393216
  short* wqT     = (short*)(ws + 60948480);   //  4718592
  short* woT     = (short*)(ws + 65667072);   //  4718592
  short* wkvT    = (short*)(ws + 70385664);   //  2359296
  short* wkvipT  = (short*)(ws + 72744960);   //  2359296
  // total 75104256 bytes

  // --- pre-pass: convert/pack/transpose to bf16 ---
  conv_bf16_kernel<<<12288, 256, 0, stream>>>(hs, hsbf, 8192 * 1536 / 4);
  enc_pack_kernel<<<1728, 256, 0, stream>>>(enc, textbf, ipbf);
  prep_weights_kernel<<<dim3(48, 48, 6), 256, 0, stream>>>(
      wq, wo, wk, wv, wkip, wvip, wqT, woT, wkvT, wkvipT);

  // --- projections ---
  q_proj_128p<<<768, 256, 0, stream>>>(hsbf, wqT, rc, rsn, qbuf);
  kv_gemm<<<dim3(12, 16), 256, 0, stream>>>(textbf, wkvT, kbuf, vtbuf, 9);
  kv_gemm<<<dim3(12, 2), 256, 0, stream>>>(ipbf, wkvipT, kipbuf, vtipbuf, 6);

  // --- attention ---
  attn_kernel<<<3072, 256, 0, stream>>>(qbuf, kbuf, vtbuf, kipbuf,
                                        vtipbuf, attnbuf);

  // --- output projection + bias + residual ---
  o_proj_128p<<<768, 256, 0, stream>>>(attnbuf, woT, bo, hs, out);
}

// Round 7
// 216.154 us; speedup vs baseline: 3.7952x; 1.0395x over previous
//
#include <hip/hip_runtime.h>
#include <hip/hip_bf16.h>

typedef __attribute__((ext_vector_type(8))) short short8;
typedef __attribute__((ext_vector_type(4))) short short4v;
typedef __attribute__((ext_vector_type(4))) float f32x4;

#define MFMA16(a, b, c) __builtin_amdgcn_mfma_f32_16x16x32_bf16(a, b, c, 0, 0, 0)
#define QK_SCALE_LOG2E 0.18033688011112042f  // (1/8) * log2(e)

__device__ __forceinline__ short f2bf(float x) {
  union { float f; unsigned u; } v; v.f = x;
  unsigned u = v.u;
  u += 0x7FFFu + ((u >> 16) & 1u);  // RNE
  return (short)(u >> 16);
}
__device__ __forceinline__ short f2bf_trunc(float x) {
  union { float f; unsigned u; } v; v.f = x;
  return (short)(v.u >> 16);
}

__device__ __forceinline__ void gload16(const void* g, void* l) {
  __builtin_amdgcn_global_load_lds(
      (const __attribute__((address_space(1))) unsigned int*)g,
      (__attribute__((address_space(3))) unsigned int*)l, 16, 0, 0);
}

// ---------------------------------------------------------------------------
// Pre-pass kernels: f32 -> bf16 convert / pack / transpose
// ---------------------------------------------------------------------------
__global__ __launch_bounds__(256) void conv_bf16_kernel(
    const float* __restrict__ in, short* __restrict__ out, int n4) {
  int i = blockIdx.x * 256 + threadIdx.x;
  if (i >= n4) return;
  f32x4 v = *(const f32x4*)(in + (size_t)i * 4);
  short4v s;
  s[0] = f2bf(v[0]); s[1] = f2bf(v[1]); s[2] = f2bf(v[2]); s[3] = f2bf(v[3]);
  *(short4v*)(out + (size_t)i * 4) = s;
}

// enc (4 x 576 x 768 f32) -> text_bf (4*512 x 768) + ip_bf (4*64 x 768)
__global__ __launch_bounds__(256) void enc_pack_kernel(
    const float* __restrict__ enc, short* __restrict__ text,
    short* __restrict__ ip) {
  int i4 = blockIdx.x * 256 + threadIdx.x;
  int i = i4 * 4;
  if (i >= 4 * 576 * 768) return;
  int c = i % 768;
  int rs = i / 768;
  int b = rs / 576, s = rs % 576;
  f32x4 v = *(const f32x4*)(enc + i);
  short4v o;
  o[0] = f2bf(v[0]); o[1] = f2bf(v[1]); o[2] = f2bf(v[2]); o[3] = f2bf(v[3]);
  if (s < 512)
    *(short4v*)(text + (size_t)(b * 512 + s) * 768 + c) = o;
  else
    *(short4v*)(ip + (size_t)(b * 64 + (s - 512)) * 768 + c) = o;
}

// All weight transposes fused: z selects which square weight to transpose.
__global__ __launch_bounds__(256) void prep_weights_kernel(
    const float* __restrict__ wq, const float* __restrict__ wo,
    const float* __restrict__ wk, const float* __restrict__ wv,
    const float* __restrict__ wkip, const float* __restrict__ wvip,
    short* __restrict__ wqT, short* __restrict__ woT,
    short* __restrict__ wkvT, short* __restrict__ wkvipT) {
  __shared__ float tile[32][33];
  const int z = blockIdx.z;
  const float* src; short* dst; int N, row_off;
  if (z == 0)      { src = wq;   dst = wqT;    N = 1536; row_off = 0; }
  else if (z == 1) { src = wo;   dst = woT;    N = 1536; row_off = 0; }
  else if (z == 2) { src = wk;   dst = wkvT;   N = 768;  row_off = 0; }
  else if (z == 3) { src = wv;   dst = wkvT;   N = 768;  row_off = 768; }
  else if (z == 4) { src = wkip; dst = wkvipT; N = 768;  row_off = 0; }
  else             { src = wvip; dst = wkvipT; N = 768;  row_off = 768; }
  int c0 = blockIdx.x * 32, r0 = blockIdx.y * 32;
  if (c0 >= N || r0 >= N) return;
  int tx = threadIdx.x & 31, ty = threadIdx.x >> 5;  // ty 0..7
#pragma unroll
  for (int j = 0; j < 4; ++j)
    tile[ty + j * 8][tx] = src[(size_t)(r0 + ty + j * 8) * N + c0 + tx];
  __syncthreads();
#pragma unroll
  for (int j = 0; j < 4; ++j)
    dst[(size_t)(row_off + c0 + ty + j * 8) * N + r0 + tx] =
        f2bf(tile[tx][ty + j * 8]);
}

// ---------------------------------------------------------------------------
// 128x128-tile GEMM core, single-buffered (kept for small K/V projections).
// ---------------------------------------------------------------------------
__device__ __forceinline__ void gemm_core(
    const short* __restrict__ A, const short* __restrict__ Bt, int K, int lda,
    int ldb, int row0, int col0, short* sA, short* sB, f32x4 acc[4][4]) {
  const int tid = threadIdx.x;
  const int lane = tid & 63;
  const int wid = tid >> 6;
  const int wr = (wid >> 1) * 64, wc = (wid & 1) * 64;
  const int lr = lane & 15;
  const int hk = (lane >> 4) * 16;
  const int xr = (lr & 7) << 4;

  for (int kt = 0; kt < K; kt += 64) {
#pragma unroll
    for (int q = 0; q < 4; ++q) {
      int L = q * 4096 + tid * 16;
      int r = L >> 7;
      int sb = (L & 127) ^ ((r & 7) << 4);
      int srcoff = kt + (sb >> 1);
      gload16(A + (size_t)(row0 + r) * lda + srcoff, (char*)sA + L);
      gload16(Bt + (size_t)(col0 + r) * ldb + srcoff, (char*)sB + L);
    }
    __syncthreads();
#pragma unroll
    for (int kk = 0; kk < 2; ++kk) {
      short8 af[4], bf[4];
#pragma unroll
      for (int m = 0; m < 4; ++m) {
        int row = wr + m * 16 + lr;
        af[m] = *(const short8*)((const char*)sA + row * 128 +
                                 ((kk * 64 + hk) ^ xr));
      }
#pragma unroll
      for (int n = 0; n < 4; ++n) {
        int row = wc + n * 16 + lr;
        bf[n] = *(const short8*)((const char*)sB + row * 128 +
                                 ((kk * 64 + hk) ^ xr));
      }
#pragma unroll
      for (int m = 0; m < 4; ++m)
#pragma unroll
        for (int n = 0; n < 4; ++n) acc[m][n] = MFMA16(af[m], bf[n], acc[m][n]);
    }
    __syncthreads();
  }
}

// ---------------------------------------------------------------------------
// 128x128-tile, BK=32, FULL double-buffer GEMM core (one barrier per K-tile).
// ---------------------------------------------------------------------------
__device__ __forceinline__ void stage32(const short* __restrict__ gA,
                                        const short* __restrict__ gBt,
                                        int lda, int ldb, char* buf, int tid) {
#pragma unroll
  for (int li = 0; li < 2; ++li) {
    int L = li * 4096 + tid * 16;
    int row = L >> 6;                      // 0..127
    int cb = (L & 63) ^ ((row & 3) << 4);  // inverse-swizzled source col byte
    gload16(gA + (size_t)row * lda + (cb >> 1), buf + L);
    gload16(gBt + (size_t)row * ldb + (cb >> 1), buf + 8192 + L);
  }
}

template <int K>
__device__ __forceinline__ void gemm128p(
    const short* __restrict__ A, const short* __restrict__ Bt, int lda,
    int ldb, int row0, int col0, char* sm, f32x4 acc[4][4]) {
  const int tid = threadIdx.x;
  const int lane = tid & 63, wid = tid >> 6;
  const int wr = (wid >> 1) * 64, wc = (wid & 1) * 64;
  const int lr = lane & 15;
  const int hk = (lane >> 4) * 16;   // byte col of this lane's 8-short group
  const int xr = (lr & 3) << 4;      // read-side XOR swizzle (64B rows)
  constexpr int NT = K / 32;

  const short* gA = A + (size_t)row0 * lda;
  const short* gB = Bt + (size_t)col0 * ldb;

  stage32(gA, gB, lda, ldb, sm, tid);  // tile 0 -> buf 0
  __syncthreads();

  for (int t = 0; t < NT; ++t) {
    char* cur = sm + (t & 1) * 16384;
    if (t + 1 < NT)
      stage32(gA + (t + 1) * 32, gB + (t + 1) * 32, lda, ldb,
              sm + ((t + 1) & 1) * 16384, tid);
    __builtin_amdgcn_sched_barrier(0);  // keep stage issue ahead of compute
    short8 af[4], bf[4];
#pragma unroll
    for (int m = 0; m < 4; ++m) {
      int row = wr + m * 16 + lr;
      af[m] = *(const short8*)(cur + row * 64 + (hk ^ xr));
    }
#pragma unroll
    for (int n = 0; n < 4; ++n) {
      int row = wc + n * 16 + lr;
      bf[n] = *(const short8*)(cur + 8192 + row * 64 + (hk ^ xr));
    }
#pragma unroll
    for (int m = 0; m < 4; ++m)
#pragma unroll
      for (int n = 0; n < 4; ++n) acc[m][n] = MFMA16(af[m], bf[n], acc[m][n]);
    __syncthreads();  // drains vmcnt(0)+lgkm, publishes buffer swap
  }
}

// Row-band XCD grid mapping for 768 blocks (64 row-panels x 12 col-panels).
__device__ __forceinline__ void grid128(int& row0, int& col0) {
  int bid = blockIdx.x;  // 0..767
  int x = bid & 7;
  int j = bid >> 3;      // 0..95
  row0 = (x * 8 + (j & 7)) * 128;
  col0 = (j >> 3) * 128;
}

// ---------------------------------------------------------------------------
// Q projection + RoPE + pre-scale by SCALE*log2(e) -> qbuf bf16 (B,H,S,64)
// ---------------------------------------------------------------------------
__global__ __launch_bounds__(256, 3) void q_proj_128p(
    const short* __restrict__ hsbf, const short* __restrict__ wqT,
    const float* __restrict__ rc, const float* __restrict__ rsn,
    short* __restrict__ qbuf) {
  __shared__ char sm[32768];
  f32x4 acc[4][4] = {};
  int row0, col0;
  grid128(row0, col0);
  gemm128p<1536>(hsbf, wqT, 1536, 1536, row0, col0, sm, acc);

  const int lane = threadIdx.x & 63, wid = threadIdx.x >> 6;
  const int wr = (wid >> 1) * 64, wc = (wid & 1) * 64;
  const int lr = lane & 15, lrow4 = (lane >> 4) * 4;
  const int h = (col0 + wc) >> 6;
#pragma unroll
  for (int m = 0; m < 4; ++m) {
#pragma unroll
    for (int r = 0; r < 4; ++r) {
      int grow = row0 + wr + m * 16 + lrow4 + r;
      int b = grow >> 11, t = grow & 2047;
      float v0 = acc[m][0][r], v1 = acc[m][1][r];
      float c0 = rc[t * 32 + lr], s0 = rsn[t * 32 + lr];
      float c1 = rc[t * 32 + 16 + lr], s1 = rsn[t * 32 + 16 + lr];
      float n0 = (v0 * c0 - v1 * s0) * QK_SCALE_LOG2E;
      float n1 = (v1 * c1 + v0 * s1) * QK_SCALE_LOG2E;
      short* ob = qbuf + ((size_t)(b * 24 + h) * 2048 + t) * 64;
      ob[lr] = f2bf(n0);
      ob[16 + lr] = f2bf(n1);
      ob[32 + lr] = f2bf(acc[m][2][r] * QK_SCALE_LOG2E);
      ob[48 + lr] = f2bf(acc[m][3][r] * QK_SCALE_LOG2E);
    }
  }
}

// ---------------------------------------------------------------------------
// Output projection + bias + residual -> f32
// ---------------------------------------------------------------------------
__global__ __launch_bounds__(256, 3) void o_proj_128p(
    const short* __restrict__ attnbf, const short* __restrict__ woT,
    const float* __restrict__ bo, const float* __restrict__ resid,
    float* __restrict__ out) {
  __shared__ char sm[32768];
  f32x4 acc[4][4] = {};
  int row0, col0;
  grid128(row0, col0);
  gemm128p<1536>(attnbf, woT, 1536, 1536, row0, col0, sm, acc);

  const int lane = threadIdx.x & 63, wid = threadIdx.x >> 6;
  const int wr = (wid >> 1) * 64, wc = (wid & 1) * 64;
  const int lr = lane & 15, lrow4 = (lane >> 4) * 4;
#pragma unroll
  for (int m = 0; m < 4; ++m) {
#pragma unroll
    for (int n = 0; n < 4; ++n) {
#pragma unroll
      for (int r = 0; r < 4; ++r) {
        int grow = row0 + wr + m * 16 + lrow4 + r;
        int gcol = col0 + wc + n * 16 + lr;
        size_t off = (size_t)grow * 1536 + gcol;
        out[off] = acc[m][n][r] + bo[gcol] + resid[off];
      }
    }
  }
}

// ---------------------------------------------------------------------------
// Fused K|V projection GEMM. V^T is written with a permuted key order within
// each 64-key block so the attention P->A fragment is lane-local:
//   col = (key & ~31) | ((key>>2)&3)<<3 | ((key>>4)&1)<<2 | (key&3)
// (PV sums over keys -> any per-tile key permutation is valid as long as
//  P and V use the same order; P's natural in-lane layout IS this order.)
// ---------------------------------------------------------------------------
__global__ __launch_bounds__(256) void kv_gemm(
    const short* __restrict__ Abf, const short* __restrict__ wkvT,
    short* __restrict__ kout, short* __restrict__ vtout, int rlog2) {
  __shared__ short sA[128 * 64];
  __shared__ short sB[128 * 64];
  f32x4 acc[4][4] = {};
  const int row0 = blockIdx.y * 128, col0 = blockIdx.x * 128;
  gemm_core(Abf, wkvT, 768, 768, 768, row0, col0, sA, sB, acc);

  const int tid = threadIdx.x;
  const int lane = tid & 63, wid = tid >> 6;
  const int wr = (wid >> 1) * 64, wc = (wid & 1) * 64;
  const int lr = lane & 15, lrow4 = (lane >> 4) * 4;
  const int rmask = (1 << rlog2) - 1;
#pragma unroll
  for (int m = 0; m < 4; ++m) {
#pragma unroll
    for (int n = 0; n < 4; ++n) {
#pragma unroll
      for (int r = 0; r < 4; ++r) {
        int grow = row0 + wr + m * 16 + lrow4 + r;
        int gcol = col0 + wc + n * 16 + lr;
        int b = grow >> rlog2, key = grow & rmask;
        short val = f2bf(acc[m][n][r]);
        if (gcol < 768) {
          int kvh = gcol >> 6, d = gcol & 63;
          kout[((((size_t)(b * 12 + kvh)) << rlog2) + key) * 64 + d] = val;
        } else {
          int c2 = gcol - 768;
          int kvh = c2 >> 6, d = c2 & 63;
          int kp = (key & ~31) | (((key >> 2) & 3) << 3) |
                   (((key >> 4) & 1) << 2) | (key & 3);
          vtout[(((size_t)((b * 12 + kvh) * 64 + d)) << rlog2) + kp] = val;
        }
      }
    }
  }
}

// ---------------------------------------------------------------------------
// Attention: block = (b, h, 64 q rows), 4 waves x 16 q-rows.
// Swapped QK^T; P kept fully in-register (key-permuted V^T makes the PV
// A-fragment lane-local); per-lane deferred max (no shfl in steady state);
// per-lane partial l reduced once at the end. LDS: K/V tiles only (32 KB).
// ---------------------------------------------------------------------------
__device__ __forceinline__ void stage_tile(const short* __restrict__ ks,
                                           const short* __restrict__ vs,
                                           int vstr, short* kb, short* vb,
                                           int tid) {
#pragma unroll
  for (int q = 0; q < 2; ++q) {
    int L = q * 4096 + tid * 16;
    int row = L >> 7;
    int sc = ((L & 127) ^ ((row & 7) << 4)) >> 1;
    gload16(ks + row * 64 + sc, (char*)kb + L);
    gload16(vs + (size_t)row * vstr + sc, (char*)vb + L);
  }
}

__device__ __forceinline__ void attn_tile(const short* kb, const short* vb,
                                          const short8 qf[2],
                                          float& m_run, float& l_run,
                                          f32x4 o_acc[4], int lane) {
  const int lr = lane & 15, hi = lane >> 4;
  // ---- QK^T (swapped: A=K rows, B=Q rows); s[nf][r]: key=16nf+4hi+r, q=lr
  f32x4 s[4];
#pragma unroll
  for (int nf = 0; nf < 4; ++nf) {
    int row = nf * 16 + lr;
    int rx = (row & 7) << 4;
    const char* base = (const char*)kb + row * 128;
    short8 k0 = *(const short8*)(base + ((hi * 16) ^ rx));
    short8 k1 = *(const short8*)(base + ((64 + hi * 16) ^ rx));
    f32x4 a = {0.f, 0.f, 0.f, 0.f};
    a = MFMA16(k0, qf[0], a);
    a = MFMA16(k1, qf[1], a);
    s[nf] = a;
  }
  // ---- per-lane max over this lane's 16 scores (no cross-lane) ----
  float mx = fmaxf(fmaxf(s[0][0], s[0][1]), fmaxf(s[0][2], s[0][3]));
#pragma unroll
  for (int nf = 1; nf < 4; ++nf)
    mx = fmaxf(mx, fmaxf(fmaxf(s[nf][0], s[nf][1]), fmaxf(s[nf][2], s[nf][3])));
  // ---- deferred rescale: cross-lane work only when the gate fires ----
  if (__any(mx - m_run > 8.0f)) {
    float mr = fmaxf(mx, __shfl_xor(mx, 16));
    mr = fmaxf(mr, __shfl_xor(mr, 32));
    float mn = fmaxf(m_run, mr);
    float corr = __builtin_amdgcn_exp2f(m_run - mn);
    m_run = mn;
    l_run *= corr;
#pragma unroll
    for (int r = 0; r < 4; ++r) {
      float cr = __shfl(corr, hi * 4 + r);
#pragma unroll
      for (int no = 0; no < 4; ++no) o_acc[no][r] *= cr;
    }
  }
  // ---- exp2 + per-lane partial sum + lane-local A-fragment pack ----
  short8 pa[2];
#pragma unroll
  for (int nf = 0; nf < 4; ++nf) {
#pragma unroll
    for (int r = 0; r < 4; ++r) {
      float p = __builtin_amdgcn_exp2f(s[nf][r] - m_run);
      l_run += p;
      pa[nf >> 1][(nf & 1) * 4 + r] = f2bf_trunc(p);
    }
  }
  // ---- PV: A = pa (in-register), B = permuted V^T from LDS ----
#pragma unroll
  for (int ks = 0; ks < 2; ++ks) {
#pragma unroll
    for (int no = 0; no < 4; ++no) {
      int row = no * 16 + lr;
      int rx = (row & 7) << 4;
      short8 vf = *(const short8*)((const char*)vb + row * 128 +
                                   ((ks * 64 + hi * 16) ^ rx));
      o_acc[no] = MFMA16(pa[ks], vf, o_acc[no]);
    }
  }
}

__global__ __launch_bounds__(256, 4) void attn_kernel(
    const short* __restrict__ qbuf, const short* __restrict__ kbuf,
    const short* __restrict__ vtbuf, const short* __restrict__ kipbuf,
    const short* __restrict__ vtipbuf, short* __restrict__ attn_out) {
  const int tid = threadIdx.x;
  const int lane = tid & 63, wid = tid >> 6;
  const int f = (blockIdx.x & 7) * 384 + (blockIdx.x >> 3);
  const int qt = f & 31;
  const int h = (f >> 5) % 24;
  const int b = f / (32 * 24);
  const int kvh = h >> 1;
  const int lr = lane & 15, hi = lane >> 4;

  __shared__ short skv_k[2 * 64 * 64];
  __shared__ short skv_v[2 * 64 * 64];

  const short* qp = qbuf + (size_t)(b * 24 + h) * 2048 * 64;
  const short* kp = kbuf + (size_t)(b * 12 + kvh) * 512 * 64;
  const short* vp = vtbuf + (size_t)(b * 12 + kvh) * 64 * 512;
  const short* kip = kipbuf + (size_t)(b * 12 + kvh) * 64 * 64;
  const short* vip = vtipbuf + (size_t)(b * 12 + kvh) * 64 * 64;

  const int q0 = qt * 64 + wid * 16;
  short8 qf[2];
  qf[0] = *(const short8*)(qp + (size_t)(q0 + lr) * 64 + hi * 8);
  qf[1] = *(const short8*)(qp + (size_t)(q0 + lr) * 64 + 32 + hi * 8);

  float m1 = -1.0e30f, l1 = 0.f, m2 = -1.0e30f, l2 = 0.f;
  f32x4 oacc1[4] = {}, oacc2[4] = {};

  stage_tile(kp, vp, 512, skv_k, skv_v, tid);
  __syncthreads();

  for (int t = 0; t < 9; ++t) {
    int cur = t & 1, nxt = cur ^ 1;
    if (t < 8) {
      const short* ks_ = (t < 7) ? kp + (t + 1) * 64 * 64 : kip;
      const short* vs_ = (t < 7) ? vp + (t + 1) * 64 : vip;
      int vstr = (t < 7) ? 512 : 64;
      stage_tile(ks_, vs_, vstr, skv_k + nxt * 4096, skv_v + nxt * 4096, tid);
    }
    if (t < 8)
      attn_tile(skv_k + cur * 4096, skv_v + cur * 4096, qf, m1, l1, oacc1, lane);
    else
      attn_tile(skv_k + cur * 4096, skv_v + cur * 4096, qf, m2, l2, oacc2, lane);
    __syncthreads();
  }

  // reduce per-lane partial l across the 4 lanes holding each q-row
  l1 += __shfl_xor(l1, 16); l1 += __shfl_xor(l1, 32);
  l2 += __shfl_xor(l2, 16); l2 += __shfl_xor(l2, 32);
  float inv1 = 1.0f / l1, inv2 = 1.0f / l2;
#pragma unroll
  for (int r = 0; r < 4; ++r) {
    float i1 = __shfl(inv1, hi * 4 + r);
    float i2 = __shfl(inv2, hi * 4 + r);
    int grow = b * 2048 + q0 + hi * 4 + r;
#pragma unroll
    for (int no = 0; no < 4; ++no) {
      float val = oacc1[no][r] * i1 + oacc2[no][r] * i2;
      attn_out[(size_t)grow * 1536 + h * 64 + no * 16 + lr] = f2bf(val);
    }
  }
}

// ---------------------------------------------------------------------------
extern "C" void kernel_launch(void* const* d_in, const int* in_sizes, int n_in,
                              void* d_out, int out_size, void* d_ws, size_t ws_size,
                              hipStream_t stream) {
  const float* hs = (const float*)d_in[0];
  const float* enc = (const float*)d_in[1];
  const float* rc = (const float*)d_in[2];
  const float* rsn = (const float*)d_in[3];
  const float* wq = (const float*)d_in[4];
  const float* wk = (const float*)d_in[5];
  const float* wv = (const float*)d_in[6];
  const float* wkip = (const float*)d_in[7];
  const float* wvip = (const float*)d_in[8];
  const float* wo = (const float*)d_in[9];
  const float* bo = (const float*)d_in[10];
  float* out = (float*)d_out;

  char* ws = (char*)d_ws;
  short* hsbf    = (short*)(ws + 0);          // 25165824 B (aliased by attnbuf)
  short* attnbuf = (short*)(ws + 0);          // reuse: hsbf dead after q_proj
  short* qbuf    = (short*)(ws + 25165824);   // 25165824
  short* kbuf    = (short*)(ws + 50331648);   //  3145728
  short* vtbuf   = (short*)(ws + 53477376);   //  3145728
  short* kipbuf  = (short*)(ws + 56623104);   //   393216
  short* vtipbuf = (short*)(ws + 57016320);   //   393216
  short* textbf  = (short*)(ws + 57409536);   //  3145728
  short* ipbf    = (short*)(ws + 60555264);   //   393216
  short* wqT     = (short*)(ws + 60948480);   //  4718592
  short* woT     = (short*)(ws + 65667072);   //  4718592
  short* wkvT    = (short*)(ws + 70385664);   //  2359296
  short* wkvipT  = (short*)(ws + 72744960);   //  2359296
  // total 75104256 bytes

  // --- pre-pass: convert/pack/transpose to bf16 ---
  conv_bf16_kernel<<<12288, 256, 0, stream>>>(hs, hsbf, 8192 * 1536 / 4);
  enc_pack_kernel<<<1728, 256, 0, stream>>>(enc, textbf, ipbf);
  prep_weights_kernel<<<dim3(48, 48, 6), 256, 0, stream>>>(
      wq, wo, wk, wv, wkip, wvip, wqT, woT, wkvT, wkvipT);

  // --- projections ---
  q_proj_128p<<<768, 256, 0, stream>>>(hsbf, wqT, rc, rsn, qbuf);
  kv_gemm<<<dim3(12, 16), 256, 0, stream>>>(textbf, wkvT, kbuf, vtbuf, 9);
  kv_gemm<<<dim3(12, 2), 256, 0, stream>>>(ipbf, wkvipT, kipbuf, vtipbuf, 6);

  // --- attention ---
  attn_kernel<<<3072, 256, 0, stream>>>(qbuf, kbuf, vtbuf, kipbuf,
                                        vtipbuf, attnbuf);

  // --- output projection + bias + residual ---
  o_proj_128p<<<768, 256, 0, stream>>>(attnbuf, woT, bo, hs, out);
}

// Round 8
// 215.885 us; speedup vs baseline: 3.7999x; 1.0012x over previous
//
#include <hip/hip_runtime.h>
#include <hip/hip_bf16.h>

typedef __attribute__((ext_vector_type(8))) short short8;
typedef __attribute__((ext_vector_type(4))) short short4v;
typedef __attribute__((ext_vector_type(4))) float f32x4;

#define MFMA16(a, b, c) __builtin_amdgcn_mfma_f32_16x16x32_bf16(a, b, c, 0, 0, 0)
#define QK_SCALE_LOG2E 0.18033688011112042f  // (1/8) * log2(e)

__device__ __forceinline__ short f2bf(float x) {
  union { float f; unsigned u; } v; v.f = x;
  unsigned u = v.u;
  u += 0x7FFFu + ((u >> 16) & 1u);  // RNE
  return (short)(u >> 16);
}
__device__ __forceinline__ short f2bf_trunc(float x) {
  union { float f; unsigned u; } v; v.f = x;
  return (short)(v.u >> 16);
}

__device__ __forceinline__ void gload16(const void* g, void* l) {
  __builtin_amdgcn_global_load_lds(
      (const __attribute__((address_space(1))) unsigned int*)g,
      (__attribute__((address_space(3))) unsigned int*)l, 16, 0, 0);
}

// ---------------------------------------------------------------------------
// Pre-pass kernels: f32 -> bf16 convert / pack / transpose
// ---------------------------------------------------------------------------
__global__ __launch_bounds__(256) void conv_bf16_kernel(
    const float* __restrict__ in, short* __restrict__ out, int n4) {
  int i = blockIdx.x * 256 + threadIdx.x;
  if (i >= n4) return;
  f32x4 v = *(const f32x4*)(in + (size_t)i * 4);
  short4v s;
  s[0] = f2bf(v[0]); s[1] = f2bf(v[1]); s[2] = f2bf(v[2]); s[3] = f2bf(v[3]);
  *(short4v*)(out + (size_t)i * 4) = s;
}

// enc (4 x 576 x 768 f32) -> text_bf (4*512 x 768) + ip_bf (4*64 x 768)
__global__ __launch_bounds__(256) void enc_pack_kernel(
    const float* __restrict__ enc, short* __restrict__ text,
    short* __restrict__ ip) {
  int i4 = blockIdx.x * 256 + threadIdx.x;
  int i = i4 * 4;
  if (i >= 4 * 576 * 768) return;
  int c = i % 768;
  int rs = i / 768;
  int b = rs / 576, s = rs % 576;
  f32x4 v = *(const f32x4*)(enc + i);
  short4v o;
  o[0] = f2bf(v[0]); o[1] = f2bf(v[1]); o[2] = f2bf(v[2]); o[3] = f2bf(v[3]);
  if (s < 512)
    *(short4v*)(text + (size_t)(b * 512 + s) * 768 + c) = o;
  else
    *(short4v*)(ip + (size_t)(b * 64 + (s - 512)) * 768 + c) = o;
}

// All weight transposes fused: z selects which square weight to transpose.
__global__ __launch_bounds__(256) void prep_weights_kernel(
    const float* __restrict__ wq, const float* __restrict__ wo,
    const float* __restrict__ wk, const float* __restrict__ wv,
    const float* __restrict__ wkip, const float* __restrict__ wvip,
    short* __restrict__ wqT, short* __restrict__ woT,
    short* __restrict__ wkvT, short* __restrict__ wkvipT) {
  __shared__ float tile[32][33];
  const int z = blockIdx.z;
  const float* src; short* dst; int N, row_off;
  if (z == 0)      { src = wq;   dst = wqT;    N = 1536; row_off = 0; }
  else if (z == 1) { src = wo;   dst = woT;    N = 1536; row_off = 0; }
  else if (z == 2) { src = wk;   dst = wkvT;   N = 768;  row_off = 0; }
  else if (z == 3) { src = wv;   dst = wkvT;   N = 768;  row_off = 768; }
  else if (z == 4) { src = wkip; dst = wkvipT; N = 768;  row_off = 0; }
  else             { src = wvip; dst = wkvipT; N = 768;  row_off = 768; }
  int c0 = blockIdx.x * 32, r0 = blockIdx.y * 32;
  if (c0 >= N || r0 >= N) return;
  int tx = threadIdx.x & 31, ty = threadIdx.x >> 5;  // ty 0..7
#pragma unroll
  for (int j = 0; j < 4; ++j)
    tile[ty + j * 8][tx] = src[(size_t)(r0 + ty + j * 8) * N + c0 + tx];
  __syncthreads();
#pragma unroll
  for (int j = 0; j < 4; ++j)
    dst[(size_t)(row_off + c0 + ty + j * 8) * N + r0 + tx] =
        f2bf(tile[tx][ty + j * 8]);
}

// ---------------------------------------------------------------------------
// 128x128-tile GEMM core, single-buffered (kept for small K/V projections).
// ---------------------------------------------------------------------------
__device__ __forceinline__ void gemm_core(
    const short* __restrict__ A, const short* __restrict__ Bt, int K, int lda,
    int ldb, int row0, int col0, short* sA, short* sB, f32x4 acc[4][4]) {
  const int tid = threadIdx.x;
  const int lane = tid & 63;
  const int wid = tid >> 6;
  const int wr = (wid >> 1) * 64, wc = (wid & 1) * 64;
  const int lr = lane & 15;
  const int hk = (lane >> 4) * 16;
  const int xr = (lr & 7) << 4;

  for (int kt = 0; kt < K; kt += 64) {
#pragma unroll
    for (int q = 0; q < 4; ++q) {
      int L = q * 4096 + tid * 16;
      int r = L >> 7;
      int sb = (L & 127) ^ ((r & 7) << 4);
      int srcoff = kt + (sb >> 1);
      gload16(A + (size_t)(row0 + r) * lda + srcoff, (char*)sA + L);
      gload16(Bt + (size_t)(col0 + r) * ldb + srcoff, (char*)sB + L);
    }
    __syncthreads();
#pragma unroll
    for (int kk = 0; kk < 2; ++kk) {
      short8 af[4], bf[4];
#pragma unroll
      for (int m = 0; m < 4; ++m) {
        int row = wr + m * 16 + lr;
        af[m] = *(const short8*)((const char*)sA + row * 128 +
                                 ((kk * 64 + hk) ^ xr));
      }
#pragma unroll
      for (int n = 0; n < 4; ++n) {
        int row = wc + n * 16 + lr;
        bf[n] = *(const short8*)((const char*)sB + row * 128 +
                                 ((kk * 64 + hk) ^ xr));
      }
#pragma unroll
      for (int m = 0; m < 4; ++m)
#pragma unroll
        for (int n = 0; n < 4; ++n) acc[m][n] = MFMA16(af[m], bf[n], acc[m][n]);
    }
    __syncthreads();
  }
}

// ---------------------------------------------------------------------------
// 128x128-tile, BK=32, FULL double-buffer GEMM core (one barrier per K-tile).
// 64B LDS rows. Swizzle f(row) = ((row>>1)&3)<<4 on BOTH sides: bank-quad =
// (row&1)*4 + (hi ^ ((row>>1)&3)) covers all 8 quads over any 16 consecutive
// rows exactly twice -> 2-way aliasing (free, m136). The old (row&3)<<4 put
// lanes lr,lr+4,lr+8,lr+12 on the same quad = 4-way conflict (4.7M/dispatch).
// ---------------------------------------------------------------------------
__device__ __forceinline__ void stage32(const short* __restrict__ gA,
                                        const short* __restrict__ gBt,
                                        int lda, int ldb, char* buf, int tid) {
#pragma unroll
  for (int li = 0; li < 2; ++li) {
    int L = li * 4096 + tid * 16;
    int row = L >> 6;                            // 0..127
    int cb = (L & 63) ^ (((row >> 1) & 3) << 4); // inverse-swizzled src col
    gload16(gA + (size_t)row * lda + (cb >> 1), buf + L);
    gload16(gBt + (size_t)row * ldb + (cb >> 1), buf + 8192 + L);
  }
}

template <int K>
__device__ __forceinline__ void gemm128p(
    const short* __restrict__ A, const short* __restrict__ Bt, int lda,
    int ldb, int row0, int col0, char* sm, f32x4 acc[4][4]) {
  const int tid = threadIdx.x;
  const int lane = tid & 63, wid = tid >> 6;
  const int wr = (wid >> 1) * 64, wc = (wid & 1) * 64;
  const int lr = lane & 15;
  const int hk = (lane >> 4) * 16;     // byte col of this lane's 8-short group
  const int xr = ((lr >> 1) & 3) << 4; // read-side XOR: rows are W+lr, W%16==0
  constexpr int NT = K / 32;

  const short* gA = A + (size_t)row0 * lda;
  const short* gB = Bt + (size_t)col0 * ldb;

  stage32(gA, gB, lda, ldb, sm, tid);  // tile 0 -> buf 0
  __syncthreads();

  for (int t = 0; t < NT; ++t) {
    char* cur = sm + (t & 1) * 16384;
    if (t + 1 < NT)
      stage32(gA + (t + 1) * 32, gB + (t + 1) * 32, lda, ldb,
              sm + ((t + 1) & 1) * 16384, tid);
    __builtin_amdgcn_sched_barrier(0);  // keep stage issue ahead of compute
    short8 af[4], bf[4];
#pragma unroll
    for (int m = 0; m < 4; ++m) {
      int row = wr + m * 16 + lr;
      af[m] = *(const short8*)(cur + row * 64 + (hk ^ xr));
    }
#pragma unroll
    for (int n = 0; n < 4; ++n) {
      int row = wc + n * 16 + lr;
      bf[n] = *(const short8*)(cur + 8192 + row * 64 + (hk ^ xr));
    }
#pragma unroll
    for (int m = 0; m < 4; ++m)
#pragma unroll
      for (int n = 0; n < 4; ++n) acc[m][n] = MFMA16(af[m], bf[n], acc[m][n]);
    __syncthreads();  // drains vmcnt(0)+lgkm, publishes buffer swap
  }
}

// Row-band XCD grid mapping for 768 blocks (64 row-panels x 12 col-panels).
__device__ __forceinline__ void grid128(int& row0, int& col0) {
  int bid = blockIdx.x;  // 0..767
  int x = bid & 7;
  int j = bid >> 3;      // 0..95
  row0 = (x * 8 + (j & 7)) * 128;
  col0 = (j >> 3) * 128;
}

// ---------------------------------------------------------------------------
// Q projection + RoPE + pre-scale by SCALE*log2(e) -> qbuf bf16 (B,H,S,64)
// ---------------------------------------------------------------------------
__global__ __launch_bounds__(256, 3) void q_proj_128p(
    const short* __restrict__ hsbf, const short* __restrict__ wqT,
    const float* __restrict__ rc, const float* __restrict__ rsn,
    short* __restrict__ qbuf) {
  __shared__ char sm[32768];
  f32x4 acc[4][4] = {};
  int row0, col0;
  grid128(row0, col0);
  gemm128p<1536>(hsbf, wqT, 1536, 1536, row0, col0, sm, acc);

  const int lane = threadIdx.x & 63, wid = threadIdx.x >> 6;
  const int wr = (wid >> 1) * 64, wc = (wid & 1) * 64;
  const int lr = lane & 15, lrow4 = (lane >> 4) * 4;
  const int h = (col0 + wc) >> 6;
#pragma unroll
  for (int m = 0; m < 4; ++m) {
#pragma unroll
    for (int r = 0; r < 4; ++r) {
      int grow = row0 + wr + m * 16 + lrow4 + r;
      int b = grow >> 11, t = grow & 2047;
      float v0 = acc[m][0][r], v1 = acc[m][1][r];
      float c0 = rc[t * 32 + lr], s0 = rsn[t * 32 + lr];
      float c1 = rc[t * 32 + 16 + lr], s1 = rsn[t * 32 + 16 + lr];
      float n0 = (v0 * c0 - v1 * s0) * QK_SCALE_LOG2E;
      float n1 = (v1 * c1 + v0 * s1) * QK_SCALE_LOG2E;
      short* ob = qbuf + ((size_t)(b * 24 + h) * 2048 + t) * 64;
      ob[lr] = f2bf(n0);
      ob[16 + lr] = f2bf(n1);
      ob[32 + lr] = f2bf(acc[m][2][r] * QK_SCALE_LOG2E);
      ob[48 + lr] = f2bf(acc[m][3][r] * QK_SCALE_LOG2E);
    }
  }
}

// ---------------------------------------------------------------------------
// Output projection + bias + residual -> f32
// ---------------------------------------------------------------------------
__global__ __launch_bounds__(256, 3) void o_proj_128p(
    const short* __restrict__ attnbf, const short* __restrict__ woT,
    const float* __restrict__ bo, const float* __restrict__ resid,
    float* __restrict__ out) {
  __shared__ char sm[32768];
  f32x4 acc[4][4] = {};
  int row0, col0;
  grid128(row0, col0);
  gemm128p<1536>(attnbf, woT, 1536, 1536, row0, col0, sm, acc);

  const int lane = threadIdx.x & 63, wid = threadIdx.x >> 6;
  const int wr = (wid >> 1) * 64, wc = (wid & 1) * 64;
  const int lr = lane & 15, lrow4 = (lane >> 4) * 4;
#pragma unroll
  for (int m = 0; m < 4; ++m) {
#pragma unroll
    for (int n = 0; n < 4; ++n) {
#pragma unroll
      for (int r = 0; r < 4; ++r) {
        int grow = row0 + wr + m * 16 + lrow4 + r;
        int gcol = col0 + wc + n * 16 + lr;
        size_t off = (size_t)grow * 1536 + gcol;
        out[off] = acc[m][n][r] + bo[gcol] + resid[off];
      }
    }
  }
}

// ---------------------------------------------------------------------------
// Fused K|V projection GEMM. V^T is written with a permuted key order within
// each 64-key block so the attention P->A fragment is lane-local:
//   col = (key & ~31) | ((key>>2)&3)<<3 | ((key>>4)&1)<<2 | (key&3)
// ---------------------------------------------------------------------------
__global__ __launch_bounds__(256) void kv_gemm(
    const short* __restrict__ Abf, const short* __restrict__ wkvT,
    short* __restrict__ kout, short* __restrict__ vtout, int rlog2) {
  __shared__ short sA[128 * 64];
  __shared__ short sB[128 * 64];
  f32x4 acc[4][4] = {};
  const int row0 = blockIdx.y * 128, col0 = blockIdx.x * 128;
  gemm_core(Abf, wkvT, 768, 768, 768, row0, col0, sA, sB, acc);

  const int tid = threadIdx.x;
  const int lane = tid & 63, wid = tid >> 6;
  const int wr = (wid >> 1) * 64, wc = (wid & 1) * 64;
  const int lr = lane & 15, lrow4 = (lane >> 4) * 4;
  const int rmask = (1 << rlog2) - 1;
#pragma unroll
  for (int m = 0; m < 4; ++m) {
#pragma unroll
    for (int n = 0; n < 4; ++n) {
#pragma unroll
      for (int r = 0; r < 4; ++r) {
        int grow = row0 + wr + m * 16 + lrow4 + r;
        int gcol = col0 + wc + n * 16 + lr;
        int b = grow >> rlog2, key = grow & rmask;
        short val = f2bf(acc[m][n][r]);
        if (gcol < 768) {
          int kvh = gcol >> 6, d = gcol & 63;
          kout[((((size_t)(b * 12 + kvh)) << rlog2) + key) * 64 + d] = val;
        } else {
          int c2 = gcol - 768;
          int kvh = c2 >> 6, d = c2 & 63;
          int kp = (key & ~31) | (((key >> 2) & 3) << 3) |
                   (((key >> 4) & 1) << 2) | (key & 3);
          vtout[(((size_t)((b * 12 + kvh) * 64 + d)) << rlog2) + kp] = val;
        }
      }
    }
  }
}

// ---------------------------------------------------------------------------
// Attention: block = (b, h, 64 q rows), 4 waves x 16 q-rows.
// Swapped QK^T; P fully in-register (key-permuted V^T); per-lane deferred
// max; per-lane partial l reduced once at the end. LDS: K/V tiles (32 KB).
// ---------------------------------------------------------------------------
__device__ __forceinline__ void stage_tile(const short* __restrict__ ks,
                                           const short* __restrict__ vs,
                                           int vstr, short* kb, short* vb,
                                           int tid) {
#pragma unroll
  for (int q = 0; q < 2; ++q) {
    int L = q * 4096 + tid * 16;
    int row = L >> 7;
    int sc = ((L & 127) ^ ((row & 7) << 4)) >> 1;
    gload16(ks + row * 64 + sc, (char*)kb + L);
    gload16(vs + (size_t)row * vstr + sc, (char*)vb + L);
  }
}

__device__ __forceinline__ void attn_tile(const short* kb, const short* vb,
                                          const short8 qf[2],
                                          float& m_run, float& l_run,
                                          f32x4 o_acc[4], int lane) {
  const int lr = lane & 15, hi = lane >> 4;
  f32x4 s[4];
#pragma unroll
  for (int nf = 0; nf < 4; ++nf) {
    int row = nf * 16 + lr;
    int rx = (row & 7) << 4;
    const char* base = (const char*)kb + row * 128;
    short8 k0 = *(const short8*)(base + ((hi * 16) ^ rx));
    short8 k1 = *(const short8*)(base + ((64 + hi * 16) ^ rx));
    f32x4 a = {0.f, 0.f, 0.f, 0.f};
    a = MFMA16(k0, qf[0], a);
    a = MFMA16(k1, qf[1], a);
    s[nf] = a;
  }
  float mx = fmaxf(fmaxf(s[0][0], s[0][1]), fmaxf(s[0][2], s[0][3]));
#pragma unroll
  for (int nf = 1; nf < 4; ++nf)
    mx = fmaxf(mx, fmaxf(fmaxf(s[nf][0], s[nf][1]), fmaxf(s[nf][2], s[nf][3])));
  if (__any(mx - m_run > 8.0f)) {
    float mr = fmaxf(mx, __shfl_xor(mx, 16));
    mr = fmaxf(mr, __shfl_xor(mr, 32));
    float mn = fmaxf(m_run, mr);
    float corr = __builtin_amdgcn_exp2f(m_run - mn);
    m_run = mn;
    l_run *= corr;
#pragma unroll
    for (int r = 0; r < 4; ++r) {
      float cr = __shfl(corr, hi * 4 + r);
#pragma unroll
      for (int no = 0; no < 4; ++no) o_acc[no][r] *= cr;
    }
  }
  short8 pa[2];
#pragma unroll
  for (int nf = 0; nf < 4; ++nf) {
#pragma unroll
    for (int r = 0; r < 4; ++r) {
      float p = __builtin_amdgcn_exp2f(s[nf][r] - m_run);
      l_run += p;
      pa[nf >> 1][(nf & 1) * 4 + r] = f2bf_trunc(p);
    }
  }
#pragma unroll
  for (int ks = 0; ks < 2; ++ks) {
#pragma unroll
    for (int no = 0; no < 4; ++no) {
      int row = no * 16 + lr;
      int rx = (row & 7) << 4;
      short8 vf = *(const short8*)((const char*)vb + row * 128 +
                                   ((ks * 64 + hi * 16) ^ rx));
      o_acc[no] = MFMA16(pa[ks], vf, o_acc[no]);
    }
  }
}

__global__ __launch_bounds__(256, 4) void attn_kernel(
    const short* __restrict__ qbuf, const short* __restrict__ kbuf,
    const short* __restrict__ vtbuf, const short* __restrict__ kipbuf,
    const short* __restrict__ vtipbuf, short* __restrict__ attn_out) {
  const int tid = threadIdx.x;
  const int lane = tid & 63, wid = tid >> 6;
  const int f = (blockIdx.x & 7) * 384 + (blockIdx.x >> 3);
  const int qt = f & 31;
  const int h = (f >> 5) % 24;
  const int b = f / (32 * 24);
  const int kvh = h >> 1;
  const int lr = lane & 15, hi = lane >> 4;

  __shared__ short skv_k[2 * 64 * 64];
  __shared__ short skv_v[2 * 64 * 64];

  const short* qp = qbuf + (size_t)(b * 24 + h) * 2048 * 64;
  const short* kp = kbuf + (size_t)(b * 12 + kvh) * 512 * 64;
  const short* vp = vtbuf + (size_t)(b * 12 + kvh) * 64 * 512;
  const short* kip = kipbuf + (size_t)(b * 12 + kvh) * 64 * 64;
  const short* vip = vtipbuf + (size_t)(b * 12 + kvh) * 64 * 64;

  const int q0 = qt * 64 + wid * 16;
  short8 qf[2];
  qf[0] = *(const short8*)(qp + (size_t)(q0 + lr) * 64 + hi * 8);
  qf[1] = *(const short8*)(qp + (size_t)(q0 + lr) * 64 + 32 + hi * 8);

  float m1 = -1.0e30f, l1 = 0.f, m2 = -1.0e30f, l2 = 0.f;
  f32x4 oacc1[4] = {}, oacc2[4] = {};

  stage_tile(kp, vp, 512, skv_k, skv_v, tid);
  __syncthreads();

  for (int t = 0; t < 9; ++t) {
    int cur = t & 1, nxt = cur ^ 1;
    if (t < 8) {
      const short* ks_ = (t < 7) ? kp + (t + 1) * 64 * 64 : kip;
      const short* vs_ = (t < 7) ? vp + (t + 1) * 64 : vip;
      int vstr = (t < 7) ? 512 : 64;
      stage_tile(ks_, vs_, vstr, skv_k + nxt * 4096, skv_v + nxt * 4096, tid);
    }
    if (t < 8)
      attn_tile(skv_k + cur * 4096, skv_v + cur * 4096, qf, m1, l1, oacc1, lane);
    else
      attn_tile(skv_k + cur * 4096, skv_v + cur * 4096, qf, m2, l2, oacc2, lane);
    __syncthreads();
  }

  l1 += __shfl_xor(l1, 16); l1 += __shfl_xor(l1, 32);
  l2 += __shfl_xor(l2, 16); l2 += __shfl_xor(l2, 32);
  float inv1 = 1.0f / l1, inv2 = 1.0f / l2;
#pragma unroll
  for (int r = 0; r < 4; ++r) {
    float i1 = __shfl(inv1, hi * 4 + r);
    float i2 = __shfl(inv2, hi * 4 + r);
    int grow = b * 2048 + q0 + hi * 4 + r;
#pragma unroll
    for (int no = 0; no < 4; ++no) {
      float val = oacc1[no][r] * i1 + oacc2[no][r] * i2;
      attn_out[(size_t)grow * 1536 + h * 64 + no * 16 + lr] = f2bf(val);
    }
  }
}

// ---------------------------------------------------------------------------
extern "C" void kernel_launch(void* const* d_in, const int* in_sizes, int n_in,
                              void* d_out, int out_size, void* d_ws, size_t ws_size,
                              hipStream_t stream) {
  const float* hs = (const float*)d_in[0];
  const float* enc = (const float*)d_in[1];
  const float* rc = (const float*)d_in[2];
  const float* rsn = (const float*)d_in[3];
  const float* wq = (const float*)d_in[4];
  const float* wk = (const float*)d_in[5];
  const float* wv = (const float*)d_in[6];
  const float* wkip = (const float*)d_in[7];
  const float* wvip = (const float*)d_in[8];
  const float* wo = (const float*)d_in[9];
  const float* bo = (const float*)d_in[10];
  float* out = (float*)d_out;

  char* ws = (char*)d_ws;
  short* hsbf    = (short*)(ws + 0);          // 25165824 B (aliased by attnbuf)
  short* attnbuf = (short*)(ws + 0);          // reuse: hsbf dead after q_proj
  short* qbuf    = (short*)(ws + 25165824);   // 25165824
  short* kbuf    = (short*)(ws + 50331648);   //  3145728
  short* vtbuf   = (short*)(ws + 53477376);   //  3145728
  short* kipbuf  = (short*)(ws + 56623104);   //   393216
  short* vtipbuf = (short*)(ws + 57016320);   //   393216
  short* textbf  = (short*)(ws + 57409536);   //  3145728
  short* ipbf    = (short*)(ws + 60555264);   //   393216
  short* wqT     = (short*)(ws + 60948480);   //  4718592
  short* woT     = (short*)(ws + 65667072);   //  4718592
  short* wkvT    = (short*)(ws + 70385664);   //  2359296
  short* wkvipT  = (short*)(ws + 72744960);   //  2359296
  // total 75104256 bytes

  // --- pre-pass: convert/pack/transpose to bf16 ---
  conv_bf16_kernel<<<12288, 256, 0, stream>>>(hs, hsbf, 8192 * 1536 / 4);
  enc_pack_kernel<<<1728, 256, 0, stream>>>(enc, textbf, ipbf);
  prep_weights_kernel<<<dim3(48, 48, 6), 256, 0, stream>>>(
      wq, wo, wk, wv, wkip, wvip, wqT, woT, wkvT, wkvipT);

  // --- projections ---
  q_proj_128p<<<768, 256, 0, stream>>>(hsbf, wqT, rc, rsn, qbuf);
  kv_gemm<<<dim3(12, 16), 256, 0, stream>>>(textbf, wkvT, kbuf, vtbuf, 9);
  kv_gemm<<<dim3(12, 2), 256, 0, stream>>>(ipbf, wkvipT, kipbuf, vtipbuf, 6);

  // --- attention ---
  attn_kernel<<<3072, 256, 0, stream>>>(qbuf, kbuf, vtbuf, kipbuf,
                                        vtipbuf, attnbuf);

  // --- output projection + bias + residual ---
  o_proj_128p<<<768, 256, 0, stream>>>(attnbuf, woT, bo, hs, out);
}